// Round 14
// baseline (1580.203 us; speedup 1.0000x reference)
//
#include <hip/hip_runtime.h>
#include <hip/hip_bf16.h>

#define DIN  128
#define HID  512
#define K1   256
#define NPAD 64       // fallback path only
#define BSH  7        // bucket = 128 dst nodes
#define CAPSH 12      // bucket capacity 4096 (mean 2041, 45-sigma safe)
#define EPB  4096     // edges per bucket_kernel block

typedef __attribute__((ext_vector_type(8))) short short8;
typedef __attribute__((ext_vector_type(4))) float f32x4;

__device__ inline ushort bf16rne(float f) {
    union { float f; unsigned u; } c; c.f = f;
    unsigned b = c.u + 0x7fff + ((c.u >> 16) & 1);
    return (ushort)(b >> 16);
}
__device__ inline float bf16tof(unsigned lo16) {
    union { unsigned u; float f; } c; c.u = lo16 << 16;
    return c.f;
}
__device__ __forceinline__ void gld16(const void* g, void* l) {
    __builtin_amdgcn_global_load_lds((const __attribute__((address_space(1))) unsigned int*)g,
                                     (__attribute__((address_space(3))) unsigned int*)l, 16, 0, 0);
}

// ---------------------------------------------------------------------------
// weights -> bf16 panelized LDS-image layout
// ---------------------------------------------------------------------------
__global__ void prep_w(const float* __restrict__ Wl, const float* __restrict__ Wr,
                       const float* __restrict__ Wp,
                       ushort* __restrict__ W1L, ushort* __restrict__ W2L) {
    int t = blockIdx.x * blockDim.x + threadIdx.x;
    if (t < 8 * 4 * 512) {
        int p = t >> 11, c = (t >> 9) & 3, col = t & 511;
        int k0 = p * 32 + c * 8;
        #pragma unroll
        for (int r = 0; r < 8; ++r) {
            int k = k0 + r;
            float v = (k < DIN) ? Wl[k * HID + col] : Wr[(k - DIN) * HID + col];
            W1L[(size_t)t * 8 + r] = bf16rne(v);
        }
    } else if (t < 8 * 4 * 512 + 16 * 4 * 512) {
        int t2 = t - 8 * 4 * 512;
        int p = t2 >> 11, c = (t2 >> 9) & 3, col = t2 & 511;
        int k0 = p * 32 + c * 8;
        #pragma unroll
        for (int r = 0; r < 8; ++r)
            W2L[(size_t)t2 * 8 + r] = bf16rne(Wp[(k0 + r) * HID + col]);
    }
}

__global__ void xcvt(const float* __restrict__ x, ushort* __restrict__ xb, int total4) {
    int i = blockIdx.x * blockDim.x + threadIdx.x;
    if (i >= total4) return;
    const float4 v = ((const float4*)x)[i];
    ushort4 o;
    o.x = bf16rne(v.x); o.y = bf16rne(v.y); o.z = bf16rne(v.z); o.w = bf16rne(v.w);
    ((ushort4*)xb)[i] = o;
}

// ---------------------------------------------------------------------------
// bucket pass: edges -> (dst>>7)-bucketed int2{src, dst&127} regions.
// ---------------------------------------------------------------------------
__global__ void binit_kernel(int* __restrict__ bcur, int nb) {
    int i = threadIdx.x + blockIdx.x * 1024;
    if (i < nb) bcur[i] = i << CAPSH;
}

__global__ __launch_bounds__(256) void bucket_kernel(
    const int* __restrict__ ei, int* __restrict__ bcur,
    int2* __restrict__ esed, int E, int nb) {
    __shared__ int lhist[800], lbase[800], lcur[800];
    const int t = threadIdx.x;
    for (int i = t; i < nb; i += 256) lhist[i] = 0;
    __syncthreads();
    const int e0 = blockIdx.x * EPB;
    int srcs[16], dsts[16], bs[16];
    #pragma unroll
    for (int i = 0; i < 16; ++i) {
        int e = e0 + i * 256 + t;
        if (e < E) {
            srcs[i] = ei[e];
            dsts[i] = ei[E + e];
            bs[i] = dsts[i] >> BSH;
            atomicAdd(&lhist[bs[i]], 1);
        } else bs[i] = -1;
    }
    __syncthreads();
    for (int i = t; i < nb; i += 256) {
        lcur[i] = 0;
        if (lhist[i] > 0) lbase[i] = atomicAdd(&bcur[i], lhist[i]);
    }
    __syncthreads();
    #pragma unroll
    for (int i = 0; i < 16; ++i) {
        if (bs[i] >= 0) {
            int off = atomicAdd(&lcur[bs[i]], 1);
            int p = lbase[bs[i]] + off;
            if (p < ((bs[i] + 1) << CAPSH))
                esed[p] = make_int2(srcs[i], dsts[i] & 127);
        }
    }
}

// ---------------------------------------------------------------------------
// fused scatter+mean: one block per 128-node bucket, f32 accum in LDS.
// 8 edges/wave/iter, 8 independent gathers in flight. Accumulation uses
// unsafeAtomicAdd -> native ds_add_f32 (plain atomicAdd(float*) compiles to
// a CAS retry loop without -munsafe-fp-atomics: that was the 1379us bug).
// ---------------------------------------------------------------------------
__global__ __launch_bounds__(1024) void agg2_kernel(
    const ushort* __restrict__ xb, const int2* __restrict__ esed,
    const int* __restrict__ bcur, ushort* __restrict__ mb, int N) {
    __shared__ float accum[128][128];
    __shared__ int lcnt[128];
    const int t = threadIdx.x;
    const int l = t & 63;
    const int wv = t >> 6;
    const int b = blockIdx.x;

    #pragma unroll
    for (int i = 0; i < 4; ++i)
        ((float4*)accum)[t + i * 1024] = (float4){0.f, 0.f, 0.f, 0.f};
    if (t < 128) lcnt[t] = 0;
    __syncthreads();

    const int vbase = b << CAPSH;
    int valid = bcur[b] - vbase;
    if (valid > (1 << CAPSH)) valid = 1 << CAPSH;

    for (int e0 = wv * 8; e0 < valid; e0 += 128) {
        // lanes 0..7: one coalesced 64B load of 8 edges
        int2 myep = make_int2(0, 0);
        if (l < 8 && e0 + l < valid) myep = esed[vbase + e0 + l];
        if (l < 8 && e0 + l < valid) atomicAdd(&lcnt[myep.y], 1);   // int: native
        // broadcast + issue 8 independent gathers
        int srcs[8], dls[8];
        #pragma unroll
        for (int j = 0; j < 8; ++j) {
            srcs[j] = __shfl(myep.x, j, 64);
            dls[j]  = __shfl(myep.y, j, 64);
        }
        unsigned v[8];
        #pragma unroll
        for (int j = 0; j < 8; ++j)
            if (e0 + j < valid)
                v[j] = ((const unsigned*)(xb + (size_t)srcs[j] * DIN))[l];
        #pragma unroll
        for (int j = 0; j < 8; ++j)
            if (e0 + j < valid) {
                unsafeAtomicAdd(&accum[dls[j]][l * 2],     bf16tof(v[j] & 0xffffu));
                unsafeAtomicAdd(&accum[dls[j]][l * 2 + 1], bf16tof(v[j] >> 16));
            }
    }
    __syncthreads();

    // write mean: 8 threads/node, 16 feats each (coalesced 32B/thread)
    const int nl = t >> 3;
    const int fb = (t & 7) * 16;
    const int node = b * 128 + nl;
    if (node < N) {
        float rd = 1.0f / fmaxf((float)lcnt[nl], 1.0f);
        uint4 o0, o1;
        #pragma unroll
        for (int j = 0; j < 8; ++j) {
            float a0 = accum[nl][fb + 2 * j] * rd;
            float a1 = accum[nl][fb + 2 * j + 1] * rd;
            unsigned pk = (unsigned)bf16rne(a0) | ((unsigned)bf16rne(a1) << 16);
            if (j < 4) ((unsigned*)&o0)[j] = pk;
            else       ((unsigned*)&o1)[j - 4] = pk;
        }
        *(uint4*)(mb + (size_t)node * DIN + fb) = o0;
        *(uint4*)(mb + (size_t)node * DIN + fb + 8) = o1;
    }
}

// ---------------------------------------------------------------------------
// fallback-path fill + gather-mean (unbucketed, uses nbr lists)
// ---------------------------------------------------------------------------
__global__ void fill_kernel(const int* __restrict__ ei, int* __restrict__ cnt,
                            int* __restrict__ nbr, int E) {
    int e = blockIdx.x * blockDim.x + threadIdx.x;
    if (e >= E) return;
    int src = ei[e];
    int dst = ei[E + e];
    int pos = atomicAdd(cnt + dst, 1);
    if (pos < NPAD) nbr[(size_t)dst * NPAD + pos] = src;
}

__global__ __launch_bounds__(256) void agg_kernel(
    const ushort* __restrict__ xb, const int* __restrict__ cnt, const int* __restrict__ nbr,
    ushort* __restrict__ mb, int N) {
    int node = blockIdx.x * 4 + (threadIdx.x >> 6);
    if (node >= N) return;
    int l = threadIdx.x & 63;
    int cn = cnt[node];
    int cc = cn < NPAD ? cn : NPAD;
    const int* nl = nbr + (size_t)node * NPAD;
    float s0 = 0.f, s1 = 0.f;
    int i = 0;
    for (; i + 4 <= cc; i += 4) {
        int4 q = *(const int4*)(nl + i);
        unsigned v0 = ((const unsigned*)(xb + (size_t)q.x * DIN))[l];
        unsigned v1 = ((const unsigned*)(xb + (size_t)q.y * DIN))[l];
        unsigned v2 = ((const unsigned*)(xb + (size_t)q.z * DIN))[l];
        unsigned v3 = ((const unsigned*)(xb + (size_t)q.w * DIN))[l];
        s0 += bf16tof(v0 & 0xffffu) + bf16tof(v1 & 0xffffu) + bf16tof(v2 & 0xffffu) + bf16tof(v3 & 0xffffu);
        s1 += bf16tof(v0 >> 16) + bf16tof(v1 >> 16) + bf16tof(v2 >> 16) + bf16tof(v3 >> 16);
    }
    for (; i < cc; ++i) {
        int src = nl[i];
        unsigned v = ((const unsigned*)(xb + (size_t)src * DIN))[l];
        s0 += bf16tof(v & 0xffffu);
        s1 += bf16tof(v >> 16);
    }
    float rd = 1.0f / fmaxf((float)cn, 1.0f);
    unsigned o = (unsigned)bf16rne(s0 * rd) | ((unsigned)bf16rne(s1 * rd) << 16);
    ((unsigned*)(mb + (size_t)node * DIN))[l] = o;
}

// ===========================================================================
// Split-GEMM path (BMT2=128, wave tile 64x64, A+W panel-double-buffered).
// ===========================================================================
#define BMT2 128

__global__ __launch_bounds__(1024, 4) void gemm1_kernel(
    const ushort* __restrict__ xb, const ushort* __restrict__ mb,
    const ushort* __restrict__ W1L, const float* __restrict__ bl,
    ushort* __restrict__ Hb, int N) {
    __shared__ unsigned char sm[81920];
    const int t = threadIdx.x;
    const int l = t & 63, w = t >> 6;
    const int wm = w >> 3, wn = w & 7;
    const int lm = l & 15, ch = l >> 4;
    const int base = blockIdx.x * BMT2;

    if (t < 512) {
        int c = t >> 7, row = t & 127;
        int node = base + row; if (node >= N) node = N - 1;
        gld16(mb + (size_t)node * DIN + c * 8, sm + t * 16);
    }
    gld16(W1L + (size_t)t * 8,          sm + 16384 + t * 16);
    gld16(W1L + (size_t)(t + 1024) * 8, sm + 16384 + (t + 1024) * 16);
    __syncthreads();

    f32x4 acc[4][4];
    #pragma unroll
    for (int ct = 0; ct < 4; ++ct) {
        float bv = bl[wn * 64 + ct * 16 + lm];
        #pragma unroll
        for (int f = 0; f < 4; ++f) acc[f][ct] = (f32x4){bv, bv, bv, bv};
    }

    for (int p = 0; p < 8; ++p) {
        if (p < 7) {
            int nb = (p + 1) & 1;
            if (t < 512) {
                int c = t >> 7, row = t & 127;
                int node = base + row; if (node >= N) node = N - 1;
                int k0 = (p + 1) * 32 + c * 8;
                const ushort* src = (k0 < DIN) ? (mb + (size_t)node * DIN + k0)
                                               : (xb + (size_t)node * DIN + (k0 - DIN));
                gld16(src, sm + nb * 8192 + t * 16);
            }
            const ushort* wsrc = W1L + (size_t)(p + 1) * 16384;
            gld16(wsrc + (size_t)t * 8,          sm + 16384 + nb * 32768 + t * 16);
            gld16(wsrc + (size_t)(t + 1024) * 8, sm + 16384 + nb * 32768 + (t + 1024) * 16);
        }
        const unsigned ab = (p & 1) * 8192;
        const unsigned bb = 16384 + (p & 1) * 32768;
        short8 a[4], b[4];
        #pragma unroll
        for (int f = 0; f < 4; ++f)
            a[f] = *(const short8*)(sm + ab + (ch * 128 + wm * 64 + f * 16 + lm) * 16);
        #pragma unroll
        for (int ct = 0; ct < 4; ++ct)
            b[ct] = *(const short8*)(sm + bb + (ch * 512 + wn * 64 + ct * 16 + lm) * 16);
        #pragma unroll
        for (int f = 0; f < 4; ++f)
            #pragma unroll
            for (int ct = 0; ct < 4; ++ct)
                acc[f][ct] = __builtin_amdgcn_mfma_f32_16x16x32_bf16(a[f], b[ct], acc[f][ct], 0, 0, 0);
        __syncthreads();
    }

    #pragma unroll
    for (int f = 0; f < 4; ++f)
        #pragma unroll
        for (int ct = 0; ct < 4; ++ct) {
            int n = wn * 64 + ct * 16 + lm;
            #pragma unroll
            for (int r = 0; r < 4; ++r) {
                int m = wm * 64 + f * 16 + ch * 4 + r;
                int node = base + m;
                if (node < N) Hb[(size_t)node * HID + n] = bf16rne(fmaxf(acc[f][ct][r], 0.0f));
            }
        }
}

__global__ __launch_bounds__(1024, 4) void gemm2_kernel(
    const ushort* __restrict__ Hb, const ushort* __restrict__ W2L,
    const float* __restrict__ bp, float* __restrict__ out, int N) {
    __shared__ unsigned char sm[81920];
    const int t = threadIdx.x;
    const int l = t & 63, w = t >> 6;
    const int wm = w >> 3, wn = w & 7;
    const int lm = l & 15, ch = l >> 4;
    const int base = blockIdx.x * BMT2;

    if (t < 512) {
        int c = t >> 7, row = t & 127;
        int node = base + row; if (node >= N) node = N - 1;
        gld16(Hb + (size_t)node * HID + c * 8, sm + t * 16);
    }
    gld16(W2L + (size_t)t * 8,          sm + 16384 + t * 16);
    gld16(W2L + (size_t)(t + 1024) * 8, sm + 16384 + (t + 1024) * 16);
    __syncthreads();

    f32x4 d[4][4];
    #pragma unroll
    for (int ct = 0; ct < 4; ++ct) {
        float bv = bp[wn * 64 + ct * 16 + lm];
        #pragma unroll
        for (int f = 0; f < 4; ++f) d[f][ct] = (f32x4){bv, bv, bv, bv};
    }

    for (int q = 0; q < 16; ++q) {
        if (q < 15) {
            int nb = (q + 1) & 1;
            if (t < 512) {
                int c = t >> 7, row = t & 127;
                int node = base + row; if (node >= N) node = N - 1;
                gld16(Hb + (size_t)node * HID + (q + 1) * 32 + c * 8, sm + nb * 8192 + t * 16);
            }
            const ushort* wsrc = W2L + (size_t)(q + 1) * 16384;
            gld16(wsrc + (size_t)t * 8,          sm + 16384 + nb * 32768 + t * 16);
            gld16(wsrc + (size_t)(t + 1024) * 8, sm + 16384 + nb * 32768 + (t + 1024) * 16);
        }
        const unsigned ab = (q & 1) * 8192;
        const unsigned bb = 16384 + (q & 1) * 32768;
        short8 a[4], b[4];
        #pragma unroll
        for (int f = 0; f < 4; ++f)
            a[f] = *(const short8*)(sm + ab + (ch * 128 + wm * 64 + f * 16 + lm) * 16);
        #pragma unroll
        for (int ct = 0; ct < 4; ++ct)
            b[ct] = *(const short8*)(sm + bb + (ch * 512 + wn * 64 + ct * 16 + lm) * 16);
        #pragma unroll
        for (int f = 0; f < 4; ++f)
            #pragma unroll
            for (int ct = 0; ct < 4; ++ct)
                d[f][ct] = __builtin_amdgcn_mfma_f32_16x16x32_bf16(a[f], b[ct], d[f][ct], 0, 0, 0);
        __syncthreads();
    }

    #pragma unroll
    for (int f = 0; f < 4; ++f)
        #pragma unroll
        for (int ct = 0; ct < 4; ++ct) {
            int n = wn * 64 + ct * 16 + lm;
            #pragma unroll
            for (int r = 0; r < 4; ++r) {
                int m = wm * 64 + f * 16 + ch * 4 + r;
                int node = base + m;
                if (node < N) out[(size_t)node * HID + n] = d[f][ct][r];
            }
        }
}

// ===========================================================================
// Fallback: R9 fused kernel (ws too small for split buffers)
// ===========================================================================
#define BMT 64
__global__ __launch_bounds__(1024, 4) void gemm_fused_kernel(
    const ushort* __restrict__ xb, const ushort* __restrict__ mb,
    const ushort* __restrict__ W1L, const ushort* __restrict__ W2L,
    const float* __restrict__ bl, const float* __restrict__ bp,
    float* __restrict__ out, int N) {
    __shared__ unsigned char sm[131072];
    const int t = threadIdx.x;
    const int l = t & 63;
    const int w = t >> 6;
    const int wm = w >> 3;
    const int wn = w & 7;
    const int lm = l & 15;
    const int ch = l >> 4;
    const int base = blockIdx.x * BMT;

    #pragma unroll
    for (int j = 0; j < 2; ++j) {
        int idx = w * 128 + j * 64 + l;
        int p = idx >> 8, c = (idx >> 6) & 3, row = idx & 63;
        int node = base + row;
        if (node >= N) node = N - 1;
        int k0 = p * 32 + c * 8;
        const ushort* src = (k0 < DIN) ? (mb + (size_t)node * DIN + k0)
                                       : (xb + (size_t)node * DIN + (k0 - DIN));
        gld16(src, sm + idx * 16);
    }
    #pragma unroll
    for (int j = 0; j < 2; ++j) {
        int ci = w * 128 + j * 64 + l;
        gld16(W1L + (size_t)ci * 8, sm + 32768 + ci * 16);
    }
    __syncthreads();

    f32x4 acc[2][4];
    #pragma unroll
    for (int ct = 0; ct < 4; ++ct) {
        float bv = bl[wn * 64 + ct * 16 + lm];
        acc[0][ct] = (f32x4){bv, bv, bv, bv};
        acc[1][ct] = acc[0][ct];
    }
    for (int p = 0; p < 8; ++p) {
        if (p < 7) {
            const ushort* wsrc = W1L + (size_t)(p + 1) * 16384;
            unsigned boff = 32768 + (((p + 1) & 1) << 15);
            #pragma unroll
            for (int j = 0; j < 2; ++j) {
                int ci = w * 128 + j * 64 + l;
                gld16(wsrc + (size_t)ci * 8, sm + boff + ci * 16);
            }
        }
        const unsigned abase = (p * 256 + ch * 64) * 16;
        const unsigned bbase = 32768 + ((p & 1) << 15) + ch * 8192;
        short8 a[2], b[4];
        #pragma unroll
        for (int f = 0; f < 2; ++f)
            a[f] = *(const short8*)(sm + abase + (wm * 32 + f * 16 + lm) * 16);
        #pragma unroll
        for (int ct = 0; ct < 4; ++ct)
            b[ct] = *(const short8*)(sm + bbase + (wn * 64 + ct * 16 + lm) * 16);
        #pragma unroll
        for (int f = 0; f < 2; ++f)
            #pragma unroll
            for (int ct = 0; ct < 4; ++ct)
                acc[f][ct] = __builtin_amdgcn_mfma_f32_16x16x32_bf16(a[f], b[ct], acc[f][ct], 0, 0, 0);
        __syncthreads();
    }

    #pragma unroll
    for (int j = 0; j < 2; ++j) {
        int ci = w * 128 + j * 64 + l;
        gld16(W2L + (size_t)ci * 8, sm + 65536 + ci * 16);
    }
    #pragma unroll
    for (int f = 0; f < 2; ++f)
        #pragma unroll
        for (int ct = 0; ct < 4; ++ct) {
            int n = wn * 64 + ct * 16 + lm;
            unsigned hb = ((n >> 5) * 256 + ((n >> 3) & 3) * 64) * 16 + (n & 7) * 2;
            #pragma unroll
            for (int r = 0; r < 4; ++r) {
                int m = wm * 32 + f * 16 + ch * 4 + r;
                *(ushort*)(sm + hb + m * 16) = bf16rne(fmaxf(acc[f][ct][r], 0.0f));
            }
        }
    __syncthreads();

    f32x4 d[2][4];
    #pragma unroll
    for (int ct = 0; ct < 4; ++ct) {
        float bv = bp[wn * 64 + ct * 16 + lm];
        d[0][ct] = (f32x4){bv, bv, bv, bv};
        d[1][ct] = d[0][ct];
    }
    for (int q = 0; q < 16; ++q) {
        if (q < 15) {
            const ushort* wsrc = W2L + (size_t)(q + 1) * 16384;
            unsigned boff = 65536 + (((q + 1) & 1) << 15);
            #pragma unroll
            for (int j = 0; j < 2; ++j) {
                int ci = w * 128 + j * 64 + l;
                gld16(wsrc + (size_t)ci * 8, sm + boff + ci * 16);
            }
        }
        const unsigned abase = (q * 256 + ch * 64) * 16;
        const unsigned bbase = 65536 + ((q & 1) << 15) + ch * 8192;
        short8 a[2], b[4];
        #pragma unroll
        for (int f = 0; f < 2; ++f)
            a[f] = *(const short8*)(sm + abase + (wm * 32 + f * 16 + lm) * 16);
        #pragma unroll
        for (int ct = 0; ct < 4; ++ct)
            b[ct] = *(const short8*)(sm + bbase + (wn * 64 + ct * 16 + lm) * 16);
        #pragma unroll
        for (int f = 0; f < 2; ++f)
            #pragma unroll
            for (int ct = 0; ct < 4; ++ct)
                d[f][ct] = __builtin_amdgcn_mfma_f32_16x16x32_bf16(a[f], b[ct], d[f][ct], 0, 0, 0);
        __syncthreads();
    }

    #pragma unroll
    for (int f = 0; f < 2; ++f)
        #pragma unroll
        for (int ct = 0; ct < 4; ++ct) {
            int n = wn * 64 + ct * 16 + lm;
            #pragma unroll
            for (int r = 0; r < 4; ++r) {
                int m = wm * 32 + f * 16 + ch * 4 + r;
                int node = base + m;
                if (node < N) out[(size_t)node * HID + n] = d[f][ct][r];
            }
        }
}

extern "C" void kernel_launch(void* const* d_in, const int* in_sizes, int n_in,
                              void* d_out, int out_size, void* d_ws, size_t ws_size,
                              hipStream_t stream) {
    const float* x  = (const float*)d_in[0];
    const int*   ei = (const int*)d_in[1];
    const float* Wl = (const float*)d_in[2];
    const float* bl = (const float*)d_in[3];
    const float* Wr = (const float*)d_in[4];
    const float* Wp = (const float*)d_in[5];
    const float* bp = (const float*)d_in[6];
    float* out = (float*)d_out;

    const int N = in_sizes[0] / DIN;
    const int E = in_sizes[1] / 2;
    const int NB = (N + 127) >> BSH;                                  // 782 buckets

    const size_t hBytes  = (size_t)N * HID * sizeof(ushort);          // 102.4 MB
    const size_t xbBytes = (size_t)N * DIN * sizeof(ushort);          // 25.6 MB
    const size_t w1Bytes = 131072 * sizeof(ushort);
    const size_t w2Bytes = 262144 * sizeof(ushort);
    const size_t bucketBytes = ((size_t)NB << CAPSH) * sizeof(int2) + NB * sizeof(int);
    const size_t needBig = hBytes + 2 * xbBytes + w1Bytes + w2Bytes;  // ~154.4 MB

    if (ws_size >= needBig && bucketBytes <= hBytes) {
        char* base = (char*)d_ws;
        // bucket scratch overlays the Hb region (dead before gemm1)
        int2*   esed = (int2*)base;                       // NB<<CAPSH entries
        int*    bcur = (int*)(esed + ((size_t)NB << CAPSH));
        ushort* Hb   = (ushort*)base;
        ushort* xb   = (ushort*)(base + hBytes);
        ushort* mb   = (ushort*)(base + hBytes + xbBytes);
        ushort* W1L  = (ushort*)(base + hBytes + 2 * xbBytes);
        ushort* W2L  = (ushort*)((char*)W1L + w1Bytes);

        prep_w<<<192, 256, 0, stream>>>(Wl, Wr, Wp, W1L, W2L);
        xcvt<<<((N * DIN / 4) + 255) / 256, 256, 0, stream>>>(x, xb, N * DIN / 4);
        binit_kernel<<<(NB + 1023) / 1024, 1024, 0, stream>>>(bcur, NB);
        bucket_kernel<<<(E + EPB - 1) / EPB, 256, 0, stream>>>(ei, bcur, esed, E, NB);
        agg2_kernel<<<NB, 1024, 0, stream>>>(xb, esed, bcur, mb, N);
        int g = (N + BMT2 - 1) / BMT2;
        gemm1_kernel<<<g, 1024, 0, stream>>>(xb, mb, W1L, bl, Hb, N);
        gemm2_kernel<<<g, 1024, 0, stream>>>(Hb, W2L, bp, out, N);
    } else {
        int*    cnt = (int*)d_ws;
        int*    nbr = cnt + N;
        ushort* xb  = (ushort*)(nbr + (size_t)N * NPAD);
        ushort* mb  = xb + (size_t)N * DIN;
        ushort* W1L = mb + (size_t)N * DIN;
        ushort* W2L = W1L + 131072;

        hipMemsetAsync(cnt, 0, (size_t)N * sizeof(int), stream);
        prep_w<<<192, 256, 0, stream>>>(Wl, Wr, Wp, W1L, W2L);
        xcvt<<<((N * DIN / 4) + 255) / 256, 256, 0, stream>>>(x, xb, N * DIN / 4);
        fill_kernel<<<(E + 255) / 256, 256, 0, stream>>>(ei, cnt, nbr, E);
        agg_kernel<<<(N + 3) / 4, 256, 0, stream>>>(xb, cnt, nbr, mb, N);
        gemm_fused_kernel<<<(N + BMT - 1) / BMT, 1024, 0, stream>>>(xb, mb, W1L, W2L, bl, bp, out, N);
    }
}

// Round 15
// 330.136 us; speedup vs baseline: 4.7865x; 4.7865x over previous
//
#include <hip/hip_runtime.h>
#include <hip/hip_bf16.h>

#define DIN  128
#define HID  512
#define K1   256
#define NPAD 96       // padded adjacency width (Poisson(16); max deg ~44; extra slack)
#define CAPSH 14      // bucket capacity 16384 (mean 8163, 91-sigma safe)
#define EPB  4096     // edges per bucket_kernel block

typedef __attribute__((ext_vector_type(8))) short short8;
typedef __attribute__((ext_vector_type(4))) float f32x4;

__device__ inline ushort bf16rne(float f) {
    union { float f; unsigned u; } c; c.f = f;
    unsigned b = c.u + 0x7fff + ((c.u >> 16) & 1);
    return (ushort)(b >> 16);
}
__device__ inline float bf16tof(unsigned lo16) {
    union { unsigned u; float f; } c; c.u = lo16 << 16;
    return c.f;
}
__device__ __forceinline__ void gld16(const void* g, void* l) {
    __builtin_amdgcn_global_load_lds((const __attribute__((address_space(1))) unsigned int*)g,
                                     (__attribute__((address_space(3))) unsigned int*)l, 16, 0, 0);
}

// ---------------------------------------------------------------------------
// weights -> bf16 panelized LDS-image layout
// ---------------------------------------------------------------------------
__global__ void prep_w(const float* __restrict__ Wl, const float* __restrict__ Wr,
                       const float* __restrict__ Wp,
                       ushort* __restrict__ W1L, ushort* __restrict__ W2L) {
    int t = blockIdx.x * blockDim.x + threadIdx.x;
    if (t < 8 * 4 * 512) {
        int p = t >> 11, c = (t >> 9) & 3, col = t & 511;
        int k0 = p * 32 + c * 8;
        #pragma unroll
        for (int r = 0; r < 8; ++r) {
            int k = k0 + r;
            float v = (k < DIN) ? Wl[k * HID + col] : Wr[(k - DIN) * HID + col];
            W1L[(size_t)t * 8 + r] = bf16rne(v);
        }
    } else if (t < 8 * 4 * 512 + 16 * 4 * 512) {
        int t2 = t - 8 * 4 * 512;
        int p = t2 >> 11, c = (t2 >> 9) & 3, col = t2 & 511;
        int k0 = p * 32 + c * 8;
        #pragma unroll
        for (int r = 0; r < 8; ++r)
            W2L[(size_t)t2 * 8 + r] = bf16rne(Wp[(k0 + r) * HID + col]);
    }
}

__global__ void xcvt(const float* __restrict__ x, ushort* __restrict__ xb, int total4) {
    int i = blockIdx.x * blockDim.x + threadIdx.x;
    if (i >= total4) return;
    const float4 v = ((const float4*)x)[i];
    ushort4 o;
    o.x = bf16rne(v.x); o.y = bf16rne(v.y); o.z = bf16rne(v.z); o.w = bf16rne(v.w);
    ((ushort4*)xb)[i] = o;
}

// ---------------------------------------------------------------------------
// bucket pass: edges -> 196 dst-buckets (dst>>9, 512-node windows).
// Block-aggregated cursors: LDS histogram -> 1 global atomic / bucket / block.
// ---------------------------------------------------------------------------
__global__ void binit_kernel(int* __restrict__ bcur) {
    bcur[threadIdx.x] = threadIdx.x << CAPSH;
}

__global__ __launch_bounds__(256) void bucket_kernel(
    const int* __restrict__ ei, int* __restrict__ bcur,
    int* __restrict__ es, int* __restrict__ ed, int E) {
    __shared__ int lhist[256], lbase[256], lcur[256];
    const int t = threadIdx.x;
    lhist[t] = 0;
    __syncthreads();
    const int e0 = blockIdx.x * EPB;
    int srcs[16], dsts[16], bs[16];
    #pragma unroll
    for (int i = 0; i < 16; ++i) {
        int e = e0 + i * 256 + t;
        if (e < E) {
            srcs[i] = ei[e];
            dsts[i] = ei[E + e];
            bs[i] = dsts[i] >> 9;
            atomicAdd(&lhist[bs[i]], 1);
        } else bs[i] = -1;
    }
    __syncthreads();
    if (lhist[t] > 0) lbase[t] = atomicAdd(&bcur[t], lhist[t]);
    lcur[t] = 0;
    __syncthreads();
    #pragma unroll
    for (int i = 0; i < 16; ++i) {
        if (bs[i] >= 0) {
            int off = atomicAdd(&lcur[bs[i]], 1);
            int p = lbase[bs[i]] + off;
            es[p] = srcs[i];
            ed[p] = dsts[i];
        }
    }
}

// ---------------------------------------------------------------------------
// fill from bucketed edges: nbr writes cluster in rotating windows -> L2-merged.
// ---------------------------------------------------------------------------
__global__ __launch_bounds__(256) void fill2_kernel(
    const int* __restrict__ es, const int* __restrict__ ed,
    const int* __restrict__ bcur, int* __restrict__ cnt,
    int* __restrict__ nbr, int nbuck) {
    int tid = blockIdx.x * 256 + threadIdx.x;
    int b = tid >> CAPSH;
    if (b >= nbuck) return;
    int valid = bcur[b] - (b << CAPSH);
    if ((tid & ((1 << CAPSH) - 1)) >= valid) return;
    int src = es[tid], dst = ed[tid];
    int pos = atomicAdd(cnt + dst, 1);
    if (pos < NPAD) nbr[(size_t)dst * NPAD + pos] = src;
}

// fallback-path fill (unbucketed)
__global__ void fill_kernel(const int* __restrict__ ei, int* __restrict__ cnt,
                            int* __restrict__ nbr, int E) {
    int e = blockIdx.x * blockDim.x + threadIdx.x;
    if (e >= E) return;
    int src = ei[e];
    int dst = ei[E + e];
    int pos = atomicAdd(cnt + dst, 1);
    if (pos < NPAD) nbr[(size_t)dst * NPAD + pos] = src;
}

// ---------------------------------------------------------------------------
// gather-mean: one wave per node; up to 16 independent row-gathers in flight.
// ---------------------------------------------------------------------------
__global__ __launch_bounds__(256) void agg_kernel(
    const ushort* __restrict__ xb, const int* __restrict__ cnt, const int* __restrict__ nbr,
    ushort* __restrict__ mb, int N) {
    int node = blockIdx.x * 4 + (threadIdx.x >> 6);
    if (node >= N) return;
    int l = threadIdx.x & 63;
    int cn = cnt[node];
    int cc = cn < NPAD ? cn : NPAD;
    const int* nl = nbr + (size_t)node * NPAD;
    float s0 = 0.f, s1 = 0.f;
    int i = 0;
    for (; i + 16 <= cc; i += 16) {
        int4 qa = *(const int4*)(nl + i);
        int4 qb = *(const int4*)(nl + i + 4);
        int4 qc = *(const int4*)(nl + i + 8);
        int4 qd = *(const int4*)(nl + i + 12);
        unsigned v0  = ((const unsigned*)(xb + (size_t)qa.x * DIN))[l];
        unsigned v1  = ((const unsigned*)(xb + (size_t)qa.y * DIN))[l];
        unsigned v2  = ((const unsigned*)(xb + (size_t)qa.z * DIN))[l];
        unsigned v3  = ((const unsigned*)(xb + (size_t)qa.w * DIN))[l];
        unsigned v4  = ((const unsigned*)(xb + (size_t)qb.x * DIN))[l];
        unsigned v5  = ((const unsigned*)(xb + (size_t)qb.y * DIN))[l];
        unsigned v6  = ((const unsigned*)(xb + (size_t)qb.z * DIN))[l];
        unsigned v7  = ((const unsigned*)(xb + (size_t)qb.w * DIN))[l];
        unsigned v8  = ((const unsigned*)(xb + (size_t)qc.x * DIN))[l];
        unsigned v9  = ((const unsigned*)(xb + (size_t)qc.y * DIN))[l];
        unsigned v10 = ((const unsigned*)(xb + (size_t)qc.z * DIN))[l];
        unsigned v11 = ((const unsigned*)(xb + (size_t)qc.w * DIN))[l];
        unsigned v12 = ((const unsigned*)(xb + (size_t)qd.x * DIN))[l];
        unsigned v13 = ((const unsigned*)(xb + (size_t)qd.y * DIN))[l];
        unsigned v14 = ((const unsigned*)(xb + (size_t)qd.z * DIN))[l];
        unsigned v15 = ((const unsigned*)(xb + (size_t)qd.w * DIN))[l];
        s0 += bf16tof(v0 & 0xffffu) + bf16tof(v1 & 0xffffu) + bf16tof(v2 & 0xffffu) + bf16tof(v3 & 0xffffu)
            + bf16tof(v4 & 0xffffu) + bf16tof(v5 & 0xffffu) + bf16tof(v6 & 0xffffu) + bf16tof(v7 & 0xffffu)
            + bf16tof(v8 & 0xffffu) + bf16tof(v9 & 0xffffu) + bf16tof(v10 & 0xffffu) + bf16tof(v11 & 0xffffu)
            + bf16tof(v12 & 0xffffu) + bf16tof(v13 & 0xffffu) + bf16tof(v14 & 0xffffu) + bf16tof(v15 & 0xffffu);
        s1 += bf16tof(v0 >> 16) + bf16tof(v1 >> 16) + bf16tof(v2 >> 16) + bf16tof(v3 >> 16)
            + bf16tof(v4 >> 16) + bf16tof(v5 >> 16) + bf16tof(v6 >> 16) + bf16tof(v7 >> 16)
            + bf16tof(v8 >> 16) + bf16tof(v9 >> 16) + bf16tof(v10 >> 16) + bf16tof(v11 >> 16)
            + bf16tof(v12 >> 16) + bf16tof(v13 >> 16) + bf16tof(v14 >> 16) + bf16tof(v15 >> 16);
    }
    for (; i + 4 <= cc; i += 4) {
        int4 q = *(const int4*)(nl + i);
        unsigned v0 = ((const unsigned*)(xb + (size_t)q.x * DIN))[l];
        unsigned v1 = ((const unsigned*)(xb + (size_t)q.y * DIN))[l];
        unsigned v2 = ((const unsigned*)(xb + (size_t)q.z * DIN))[l];
        unsigned v3 = ((const unsigned*)(xb + (size_t)q.w * DIN))[l];
        s0 += bf16tof(v0 & 0xffffu) + bf16tof(v1 & 0xffffu) + bf16tof(v2 & 0xffffu) + bf16tof(v3 & 0xffffu);
        s1 += bf16tof(v0 >> 16) + bf16tof(v1 >> 16) + bf16tof(v2 >> 16) + bf16tof(v3 >> 16);
    }
    for (; i < cc; ++i) {
        int src = nl[i];
        unsigned v = ((const unsigned*)(xb + (size_t)src * DIN))[l];
        s0 += bf16tof(v & 0xffffu);
        s1 += bf16tof(v >> 16);
    }
    float rd = 1.0f / fmaxf((float)cn, 1.0f);
    unsigned o = (unsigned)bf16rne(s0 * rd) | ((unsigned)bf16rne(s1 * rd) << 16);
    ((unsigned*)(mb + (size_t)node * DIN))[l] = o;
}

// ===========================================================================
// Split-GEMM path (BMT2=128, wave tile 64x64, A+W panel-double-buffered).
// LDS 80KB: Abuf0 @0 (8K), Abuf1 @8K, Wbuf0 @16K (32K), Wbuf1 @48K.
// ===========================================================================
#define BMT2 128

__global__ __launch_bounds__(1024, 4) void gemm1_kernel(
    const ushort* __restrict__ xb, const ushort* __restrict__ mb,
    const ushort* __restrict__ W1L, const float* __restrict__ bl,
    ushort* __restrict__ Hb, int N) {
    __shared__ unsigned char sm[81920];
    const int t = threadIdx.x;
    const int l = t & 63, w = t >> 6;
    const int wm = w >> 3, wn = w & 7;
    const int lm = l & 15, ch = l >> 4;
    const int base = blockIdx.x * BMT2;

    if (t < 512) {
        int c = t >> 7, row = t & 127;
        int node = base + row; if (node >= N) node = N - 1;
        gld16(mb + (size_t)node * DIN + c * 8, sm + t * 16);
    }
    gld16(W1L + (size_t)t * 8,          sm + 16384 + t * 16);
    gld16(W1L + (size_t)(t + 1024) * 8, sm + 16384 + (t + 1024) * 16);
    __syncthreads();

    f32x4 acc[4][4];
    #pragma unroll
    for (int ct = 0; ct < 4; ++ct) {
        float bv = bl[wn * 64 + ct * 16 + lm];
        #pragma unroll
        for (int f = 0; f < 4; ++f) acc[f][ct] = (f32x4){bv, bv, bv, bv};
    }

    for (int p = 0; p < 8; ++p) {
        if (p < 7) {
            int nb = (p + 1) & 1;
            if (t < 512) {
                int c = t >> 7, row = t & 127;
                int node = base + row; if (node >= N) node = N - 1;
                int k0 = (p + 1) * 32 + c * 8;
                const ushort* src = (k0 < DIN) ? (mb + (size_t)node * DIN + k0)
                                               : (xb + (size_t)node * DIN + (k0 - DIN));
                gld16(src, sm + nb * 8192 + t * 16);
            }
            const ushort* wsrc = W1L + (size_t)(p + 1) * 16384;
            gld16(wsrc + (size_t)t * 8,          sm + 16384 + nb * 32768 + t * 16);
            gld16(wsrc + (size_t)(t + 1024) * 8, sm + 16384 + nb * 32768 + (t + 1024) * 16);
        }
        const unsigned ab = (p & 1) * 8192;
        const unsigned bb = 16384 + (p & 1) * 32768;
        short8 a[4], b[4];
        #pragma unroll
        for (int f = 0; f < 4; ++f)
            a[f] = *(const short8*)(sm + ab + (ch * 128 + wm * 64 + f * 16 + lm) * 16);
        #pragma unroll
        for (int ct = 0; ct < 4; ++ct)
            b[ct] = *(const short8*)(sm + bb + (ch * 512 + wn * 64 + ct * 16 + lm) * 16);
        #pragma unroll
        for (int f = 0; f < 4; ++f)
            #pragma unroll
            for (int ct = 0; ct < 4; ++ct)
                acc[f][ct] = __builtin_amdgcn_mfma_f32_16x16x32_bf16(a[f], b[ct], acc[f][ct], 0, 0, 0);
        __syncthreads();
    }

    // epilogue: relu -> H bf16 (row-major [node][512])
    #pragma unroll
    for (int f = 0; f < 4; ++f)
        #pragma unroll
        for (int ct = 0; ct < 4; ++ct) {
            int n = wn * 64 + ct * 16 + lm;
            #pragma unroll
            for (int r = 0; r < 4; ++r) {
                int m = wm * 64 + f * 16 + ch * 4 + r;
                int node = base + m;
                if (node < N) Hb[(size_t)node * HID + n] = bf16rne(fmaxf(acc[f][ct][r], 0.0f));
            }
        }
}

__global__ __launch_bounds__(1024, 4) void gemm2_kernel(
    const ushort* __restrict__ Hb, const ushort* __restrict__ W2L,
    const float* __restrict__ bp, float* __restrict__ out, int N) {
    __shared__ unsigned char sm[81920];
    const int t = threadIdx.x;
    const int l = t & 63, w = t >> 6;
    const int wm = w >> 3, wn = w & 7;
    const int lm = l & 15, ch = l >> 4;
    const int base = blockIdx.x * BMT2;

    if (t < 512) {
        int c = t >> 7, row = t & 127;
        int node = base + row; if (node >= N) node = N - 1;
        gld16(Hb + (size_t)node * HID + c * 8, sm + t * 16);
    }
    gld16(W2L + (size_t)t * 8,          sm + 16384 + t * 16);
    gld16(W2L + (size_t)(t + 1024) * 8, sm + 16384 + (t + 1024) * 16);
    __syncthreads();

    f32x4 d[4][4];
    #pragma unroll
    for (int ct = 0; ct < 4; ++ct) {
        float bv = bp[wn * 64 + ct * 16 + lm];
        #pragma unroll
        for (int f = 0; f < 4; ++f) d[f][ct] = (f32x4){bv, bv, bv, bv};
    }

    for (int q = 0; q < 16; ++q) {
        if (q < 15) {
            int nb = (q + 1) & 1;
            if (t < 512) {
                int c = t >> 7, row = t & 127;
                int node = base + row; if (node >= N) node = N - 1;
                gld16(Hb + (size_t)node * HID + (q + 1) * 32 + c * 8, sm + nb * 8192 + t * 16);
            }
            const ushort* wsrc = W2L + (size_t)(q + 1) * 16384;
            gld16(wsrc + (size_t)t * 8,          sm + 16384 + nb * 32768 + t * 16);
            gld16(wsrc + (size_t)(t + 1024) * 8, sm + 16384 + nb * 32768 + (t + 1024) * 16);
        }
        const unsigned ab = (q & 1) * 8192;
        const unsigned bb = 16384 + (q & 1) * 32768;
        short8 a[4], b[4];
        #pragma unroll
        for (int f = 0; f < 4; ++f)
            a[f] = *(const short8*)(sm + ab + (ch * 128 + wm * 64 + f * 16 + lm) * 16);
        #pragma unroll
        for (int ct = 0; ct < 4; ++ct)
            b[ct] = *(const short8*)(sm + bb + (ch * 512 + wn * 64 + ct * 16 + lm) * 16);
        #pragma unroll
        for (int f = 0; f < 4; ++f)
            #pragma unroll
            for (int ct = 0; ct < 4; ++ct)
                d[f][ct] = __builtin_amdgcn_mfma_f32_16x16x32_bf16(a[f], b[ct], d[f][ct], 0, 0, 0);
        __syncthreads();
    }

    #pragma unroll
    for (int f = 0; f < 4; ++f)
        #pragma unroll
        for (int ct = 0; ct < 4; ++ct) {
            int n = wn * 64 + ct * 16 + lm;
            #pragma unroll
            for (int r = 0; r < 4; ++r) {
                int m = wm * 64 + f * 16 + ch * 4 + r;
                int node = base + m;
                if (node < N) out[(size_t)node * HID + n] = d[f][ct][r];
            }
        }
}

// ===========================================================================
// Fallback: fused kernel (ws too small for split buffers)
// ===========================================================================
#define BMT 64
__global__ __launch_bounds__(1024, 4) void gemm_fused_kernel(
    const ushort* __restrict__ xb, const ushort* __restrict__ mb,
    const ushort* __restrict__ W1L, const ushort* __restrict__ W2L,
    const float* __restrict__ bl, const float* __restrict__ bp,
    float* __restrict__ out, int N) {
    __shared__ unsigned char sm[131072];
    const int t = threadIdx.x;
    const int l = t & 63;
    const int w = t >> 6;
    const int wm = w >> 3;
    const int wn = w & 7;
    const int lm = l & 15;
    const int ch = l >> 4;
    const int base = blockIdx.x * BMT;

    #pragma unroll
    for (int j = 0; j < 2; ++j) {
        int idx = w * 128 + j * 64 + l;
        int p = idx >> 8, c = (idx >> 6) & 3, row = idx & 63;
        int node = base + row;
        if (node >= N) node = N - 1;
        int k0 = p * 32 + c * 8;
        const ushort* src = (k0 < DIN) ? (mb + (size_t)node * DIN + k0)
                                       : (xb + (size_t)node * DIN + (k0 - DIN));
        gld16(src, sm + idx * 16);
    }
    #pragma unroll
    for (int j = 0; j < 2; ++j) {
        int ci = w * 128 + j * 64 + l;
        gld16(W1L + (size_t)ci * 8, sm + 32768 + ci * 16);
    }
    __syncthreads();

    f32x4 acc[2][4];
    #pragma unroll
    for (int ct = 0; ct < 4; ++ct) {
        float bv = bl[wn * 64 + ct * 16 + lm];
        acc[0][ct] = (f32x4){bv, bv, bv, bv};
        acc[1][ct] = acc[0][ct];
    }
    for (int p = 0; p < 8; ++p) {
        if (p < 7) {
            const ushort* wsrc = W1L + (size_t)(p + 1) * 16384;
            unsigned boff = 32768 + (((p + 1) & 1) << 15);
            #pragma unroll
            for (int j = 0; j < 2; ++j) {
                int ci = w * 128 + j * 64 + l;
                gld16(wsrc + (size_t)ci * 8, sm + boff + ci * 16);
            }
        }
        const unsigned abase = (p * 256 + ch * 64) * 16;
        const unsigned bbase = 32768 + ((p & 1) << 15) + ch * 8192;
        short8 a[2], b[4];
        #pragma unroll
        for (int f = 0; f < 2; ++f)
            a[f] = *(const short8*)(sm + abase + (wm * 32 + f * 16 + lm) * 16);
        #pragma unroll
        for (int ct = 0; ct < 4; ++ct)
            b[ct] = *(const short8*)(sm + bbase + (wn * 64 + ct * 16 + lm) * 16);
        #pragma unroll
        for (int f = 0; f < 2; ++f)
            #pragma unroll
            for (int ct = 0; ct < 4; ++ct)
                acc[f][ct] = __builtin_amdgcn_mfma_f32_16x16x32_bf16(a[f], b[ct], acc[f][ct], 0, 0, 0);
        __syncthreads();
    }

    #pragma unroll
    for (int j = 0; j < 2; ++j) {
        int ci = w * 128 + j * 64 + l;
        gld16(W2L + (size_t)ci * 8, sm + 65536 + ci * 16);
    }
    #pragma unroll
    for (int f = 0; f < 2; ++f)
        #pragma unroll
        for (int ct = 0; ct < 4; ++ct) {
            int n = wn * 64 + ct * 16 + lm;
            unsigned hb = ((n >> 5) * 256 + ((n >> 3) & 3) * 64) * 16 + (n & 7) * 2;
            #pragma unroll
            for (int r = 0; r < 4; ++r) {
                int m = wm * 32 + f * 16 + ch * 4 + r;
                *(ushort*)(sm + hb + m * 16) = bf16rne(fmaxf(acc[f][ct][r], 0.0f));
            }
        }
    __syncthreads();

    f32x4 d[2][4];
    #pragma unroll
    for (int ct = 0; ct < 4; ++ct) {
        float bv = bp[wn * 64 + ct * 16 + lm];
        d[0][ct] = (f32x4){bv, bv, bv, bv};
        d[1][ct] = d[0][ct];
    }
    for (int q = 0; q < 16; ++q) {
        if (q < 15) {
            const ushort* wsrc = W2L + (size_t)(q + 1) * 16384;
            unsigned boff = 65536 + (((q + 1) & 1) << 15);
            #pragma unroll
            for (int j = 0; j < 2; ++j) {
                int ci = w * 128 + j * 64 + l;
                gld16(wsrc + (size_t)ci * 8, sm + boff + ci * 16);
            }
        }
        const unsigned abase = (q * 256 + ch * 64) * 16;
        const unsigned bbase = 65536 + ((q & 1) << 15) + ch * 8192;
        short8 a[2], b[4];
        #pragma unroll
        for (int f = 0; f < 2; ++f)
            a[f] = *(const short8*)(sm + abase + (wm * 32 + f * 16 + lm) * 16);
        #pragma unroll
        for (int ct = 0; ct < 4; ++ct)
            b[ct] = *(const short8*)(sm + bbase + (wn * 64 + ct * 16 + lm) * 16);
        #pragma unroll
        for (int f = 0; f < 2; ++f)
            #pragma unroll
            for (int ct = 0; ct < 4; ++ct)
                d[f][ct] = __builtin_amdgcn_mfma_f32_16x16x32_bf16(a[f], b[ct], d[f][ct], 0, 0, 0);
        __syncthreads();
    }

    #pragma unroll
    for (int f = 0; f < 2; ++f)
        #pragma unroll
        for (int ct = 0; ct < 4; ++ct) {
            int n = wn * 64 + ct * 16 + lm;
            #pragma unroll
            for (int r = 0; r < 4; ++r) {
                int m = wm * 32 + f * 16 + ch * 4 + r;
                int node = base + m;
                if (node < N) out[(size_t)node * HID + n] = d[f][ct][r];
            }
        }
}

extern "C" void kernel_launch(void* const* d_in, const int* in_sizes, int n_in,
                              void* d_out, int out_size, void* d_ws, size_t ws_size,
                              hipStream_t stream) {
    const float* x  = (const float*)d_in[0];
    const int*   ei = (const int*)d_in[1];
    const float* Wl = (const float*)d_in[2];
    const float* bl = (const float*)d_in[3];
    const float* Wr = (const float*)d_in[4];
    const float* Wp = (const float*)d_in[5];
    const float* bp = (const float*)d_in[6];
    float* out = (float*)d_out;

    const int N = in_sizes[0] / DIN;
    const int E = in_sizes[1] / 2;
    const int nbuck = (N + 511) >> 9;

    const size_t hBytes  = (size_t)N * HID * sizeof(ushort);          // 102.4 MB
    const size_t xbBytes = (size_t)N * DIN * sizeof(ushort);          // 25.6 MB
    const size_t w1Bytes = 131072 * sizeof(ushort);
    const size_t w2Bytes = 262144 * sizeof(ushort);
    const size_t esSlots = (size_t)256 << CAPSH;                      // 4.19M slots
    const size_t needBig = hBytes + 2 * xbBytes + w1Bytes + w2Bytes
                         + 2 * esSlots * sizeof(int);                 // ~188 MB

    if (ws_size >= needBig) {
        char* base = (char*)d_ws;
        // pre-phase scratch overlays the Hb region (all dead before gemm1)
        int*    cnt  = (int*)base;                      // N ints
        int*    nbr  = cnt + N;                         // N*NPAD ints
        int*    bcur = nbr + (size_t)N * NPAD;          // 256 ints
        ushort* Hb   = (ushort*)base;
        ushort* xb   = (ushort*)(base + hBytes);
        ushort* mb   = (ushort*)(base + hBytes + xbBytes);
        ushort* W1L  = (ushort*)(base + hBytes + 2 * xbBytes);
        ushort* W2L  = (ushort*)((char*)W1L + w1Bytes);
        int*    es   = (int*)((char*)W2L + w2Bytes);
        int*    ed   = es + esSlots;

        hipMemsetAsync(cnt, 0, (size_t)N * sizeof(int), stream);
        binit_kernel<<<1, 256, 0, stream>>>(bcur);
        prep_w<<<192, 256, 0, stream>>>(Wl, Wr, Wp, W1L, W2L);
        xcvt<<<((N * DIN / 4) + 255) / 256, 256, 0, stream>>>(x, xb, N * DIN / 4);
        bucket_kernel<<<(E + EPB - 1) / EPB, 256, 0, stream>>>(ei, bcur, es, ed, E);
        fill2_kernel<<<(nbuck << CAPSH) / 256, 256, 0, stream>>>(es, ed, bcur, cnt, nbr, nbuck);
        agg_kernel<<<(N + 3) / 4, 256, 0, stream>>>(xb, cnt, nbr, mb, N);
        int g = (N + BMT2 - 1) / BMT2;
        gemm1_kernel<<<g, 1024, 0, stream>>>(xb, mb, W1L, bl, Hb, N);
        gemm2_kernel<<<g, 1024, 0, stream>>>(Hb, W2L, bp, out, N);
    } else {
        int*    cnt = (int*)d_ws;
        int*    nbr = cnt + N;
        ushort* xb  = (ushort*)(nbr + (size_t)N * NPAD);
        ushort* mb  = xb + (size_t)N * DIN;
        ushort* W1L = mb + (size_t)N * DIN;
        ushort* W2L = W1L + 131072;

        hipMemsetAsync(cnt, 0, (size_t)N * sizeof(int), stream);
        prep_w<<<192, 256, 0, stream>>>(Wl, Wr, Wp, W1L, W2L);
        xcvt<<<((N * DIN / 4) + 255) / 256, 256, 0, stream>>>(x, xb, N * DIN / 4);
        fill_kernel<<<(E + 255) / 256, 256, 0, stream>>>(ei, cnt, nbr, E);
        agg_kernel<<<(N + 3) / 4, 256, 0, stream>>>(xb, cnt, nbr, mb, N);
        gemm_fused_kernel<<<(N + BMT - 1) / BMT, 1024, 0, stream>>>(xb, mb, W1L, W2L, bl, bp, out, N);
    }
}

// Round 16
// 284.750 us; speedup vs baseline: 5.5494x; 1.1594x over previous
//
#include <hip/hip_runtime.h>
#include <hip/hip_bf16.h>

#define DIN  128
#define HID  512
#define K1   256
#define NPAD 96       // fallback path only
#define BSH  8        // bucket = 256 dst nodes
#define CAPSH 13      // bucket capacity 8192 (mean 4081, ~64-sigma safe)
#define EPB  4096     // edges per bucket_kernel block

typedef __attribute__((ext_vector_type(8))) short short8;
typedef __attribute__((ext_vector_type(4))) float f32x4;

__device__ inline ushort bf16rne(float f) {
    union { float f; unsigned u; } c; c.f = f;
    unsigned b = c.u + 0x7fff + ((c.u >> 16) & 1);
    return (ushort)(b >> 16);
}
__device__ inline float bf16tof(unsigned lo16) {
    union { unsigned u; float f; } c; c.u = lo16 << 16;
    return c.f;
}
__device__ __forceinline__ void gld16(const void* g, void* l) {
    __builtin_amdgcn_global_load_lds((const __attribute__((address_space(1))) unsigned int*)g,
                                     (__attribute__((address_space(3))) unsigned int*)l, 16, 0, 0);
}

// ---------------------------------------------------------------------------
// weights -> bf16 panelized LDS-image layout
// ---------------------------------------------------------------------------
__global__ void prep_w(const float* __restrict__ Wl, const float* __restrict__ Wr,
                       const float* __restrict__ Wp,
                       ushort* __restrict__ W1L, ushort* __restrict__ W2L) {
    int t = blockIdx.x * blockDim.x + threadIdx.x;
    if (t < 8 * 4 * 512) {
        int p = t >> 11, c = (t >> 9) & 3, col = t & 511;
        int k0 = p * 32 + c * 8;
        #pragma unroll
        for (int r = 0; r < 8; ++r) {
            int k = k0 + r;
            float v = (k < DIN) ? Wl[k * HID + col] : Wr[(k - DIN) * HID + col];
            W1L[(size_t)t * 8 + r] = bf16rne(v);
        }
    } else if (t < 8 * 4 * 512 + 16 * 4 * 512) {
        int t2 = t - 8 * 4 * 512;
        int p = t2 >> 11, c = (t2 >> 9) & 3, col = t2 & 511;
        int k0 = p * 32 + c * 8;
        #pragma unroll
        for (int r = 0; r < 8; ++r)
            W2L[(size_t)t2 * 8 + r] = bf16rne(Wp[(k0 + r) * HID + col]);
    }
}

__global__ void xcvt(const float* __restrict__ x, ushort* __restrict__ xb, int total4) {
    int i = blockIdx.x * blockDim.x + threadIdx.x;
    if (i >= total4) return;
    const float4 v = ((const float4*)x)[i];
    ushort4 o;
    o.x = bf16rne(v.x); o.y = bf16rne(v.y); o.z = bf16rne(v.z); o.w = bf16rne(v.w);
    ((ushort4*)xb)[i] = o;
}

// ---------------------------------------------------------------------------
// bucket pass: edges -> (dst>>8)-bucketed packed u32 (src<<8 | dst&255).
// Block-aggregated cursors: LDS histogram -> 1 global atomic / bucket / block.
// ---------------------------------------------------------------------------
__global__ void binit_kernel(int* __restrict__ bcur, int nb) {
    int i = threadIdx.x + blockIdx.x * 1024;
    if (i < nb) bcur[i] = i << CAPSH;
}

__global__ __launch_bounds__(256) void bucket_kernel(
    const int* __restrict__ ei, int* __restrict__ bcur,
    unsigned* __restrict__ eb, int E, int nb) {
    __shared__ int lhist[400], lbase[400], lcur[400];
    const int t = threadIdx.x;
    for (int i = t; i < nb; i += 256) lhist[i] = 0;
    __syncthreads();
    const int e0 = blockIdx.x * EPB;
    int srcs[16], dsts[16], bs[16];
    #pragma unroll
    for (int i = 0; i < 16; ++i) {
        int e = e0 + i * 256 + t;
        if (e < E) {
            srcs[i] = ei[e];
            dsts[i] = ei[E + e];
            bs[i] = dsts[i] >> BSH;
            atomicAdd(&lhist[bs[i]], 1);
        } else bs[i] = -1;
    }
    __syncthreads();
    for (int i = t; i < nb; i += 256) {
        lcur[i] = 0;
        if (lhist[i] > 0) lbase[i] = atomicAdd(&bcur[i], lhist[i]);
    }
    __syncthreads();
    #pragma unroll
    for (int i = 0; i < 16; ++i) {
        if (bs[i] >= 0) {
            int off = atomicAdd(&lcur[bs[i]], 1);
            int p = lbase[bs[i]] + off;
            if (p < ((bs[i] + 1) << CAPSH))
                eb[p] = ((unsigned)srcs[i] << 8) | (unsigned)(dsts[i] & 255);
        }
    }
}

// ---------------------------------------------------------------------------
// agg3: one block per 256-node bucket, 512 threads = 8 waves.
// LDS counting sort (hist -> scan -> scatter) builds per-node src lists in
// LDS, then the PROVEN gather loop: wave-per-node, 16 gathers in flight.
// Replaces fill2 + global nbr round-trip.
// ---------------------------------------------------------------------------
__global__ __launch_bounds__(512) void agg3_kernel(
    const ushort* __restrict__ xb, const unsigned* __restrict__ eb,
    const int* __restrict__ bcur, ushort* __restrict__ mb, int N) {
    __shared__ int sLDS[1 << CAPSH];          // sorted src list (32KB)
    __shared__ int pcnt[256], tmp[256], poff[256], pcur[256];
    const int t = threadIdx.x;
    const int l = t & 63;
    const int wv = t >> 6;
    const int b = blockIdx.x;

    if (t < 256) pcnt[t] = 0;
    __syncthreads();

    const int vbase = b << CAPSH;
    int valid = bcur[b] - vbase;
    if (valid > (1 << CAPSH)) valid = 1 << CAPSH;

    // pass 1: histogram
    for (int i = t; i < valid; i += 512)
        atomicAdd(&pcnt[eb[vbase + i] & 255u], 1);
    __syncthreads();

    // Hillis-Steele inclusive scan over 256 counts
    if (t < 256) tmp[t] = pcnt[t];
    __syncthreads();
    #pragma unroll
    for (int s = 1; s < 256; s <<= 1) {
        int v = 0;
        if (t < 256) { v = tmp[t]; if (t >= s) v += tmp[t - s]; }
        __syncthreads();
        if (t < 256) tmp[t] = v;
        __syncthreads();
    }
    if (t < 256) { poff[t] = tmp[t] - pcnt[t]; pcur[t] = tmp[t] - pcnt[t]; }
    __syncthreads();

    // pass 2: scatter srcs into sorted order
    for (int i = t; i < valid; i += 512) {
        unsigned u = eb[vbase + i];
        int slot = atomicAdd(&pcur[u & 255u], 1);
        sLDS[slot] = (int)(u >> 8);
    }
    __syncthreads();

    // gather-mean: wave per node, 16 independent gathers in flight
    for (int nl = wv; nl < 256; nl += 8) {
        int node = (b << BSH) + nl;
        if (node >= N) continue;
        int cn = pcnt[nl];
        const int off = poff[nl];
        float s0 = 0.f, s1 = 0.f;
        int i = 0;
        for (; i + 16 <= cn; i += 16) {
            int s_[16];
            #pragma unroll
            for (int j = 0; j < 16; ++j) s_[j] = sLDS[off + i + j];   // broadcast
            unsigned v_[16];
            #pragma unroll
            for (int j = 0; j < 16; ++j)
                v_[j] = ((const unsigned*)(xb + (size_t)s_[j] * DIN))[l];
            #pragma unroll
            for (int j = 0; j < 16; ++j) {
                s0 += bf16tof(v_[j] & 0xffffu);
                s1 += bf16tof(v_[j] >> 16);
            }
        }
        for (; i + 4 <= cn; i += 4) {
            int s_[4];
            #pragma unroll
            for (int j = 0; j < 4; ++j) s_[j] = sLDS[off + i + j];
            unsigned v_[4];
            #pragma unroll
            for (int j = 0; j < 4; ++j)
                v_[j] = ((const unsigned*)(xb + (size_t)s_[j] * DIN))[l];
            #pragma unroll
            for (int j = 0; j < 4; ++j) {
                s0 += bf16tof(v_[j] & 0xffffu);
                s1 += bf16tof(v_[j] >> 16);
            }
        }
        for (; i < cn; ++i) {
            int src = sLDS[off + i];
            unsigned v = ((const unsigned*)(xb + (size_t)src * DIN))[l];
            s0 += bf16tof(v & 0xffffu);
            s1 += bf16tof(v >> 16);
        }
        float rd = 1.0f / fmaxf((float)cn, 1.0f);
        unsigned o = (unsigned)bf16rne(s0 * rd) | ((unsigned)bf16rne(s1 * rd) << 16);
        ((unsigned*)(mb + (size_t)node * DIN))[l] = o;
    }
}

// ---------------------------------------------------------------------------
// fallback-path fill + gather-mean (unbucketed, uses nbr lists)
// ---------------------------------------------------------------------------
__global__ void fill_kernel(const int* __restrict__ ei, int* __restrict__ cnt,
                            int* __restrict__ nbr, int E) {
    int e = blockIdx.x * blockDim.x + threadIdx.x;
    if (e >= E) return;
    int src = ei[e];
    int dst = ei[E + e];
    int pos = atomicAdd(cnt + dst, 1);
    if (pos < NPAD) nbr[(size_t)dst * NPAD + pos] = src;
}

__global__ __launch_bounds__(256) void agg_kernel(
    const ushort* __restrict__ xb, const int* __restrict__ cnt, const int* __restrict__ nbr,
    ushort* __restrict__ mb, int N) {
    int node = blockIdx.x * 4 + (threadIdx.x >> 6);
    if (node >= N) return;
    int l = threadIdx.x & 63;
    int cn = cnt[node];
    int cc = cn < NPAD ? cn : NPAD;
    const int* nl = nbr + (size_t)node * NPAD;
    float s0 = 0.f, s1 = 0.f;
    int i = 0;
    for (; i + 4 <= cc; i += 4) {
        int4 q = *(const int4*)(nl + i);
        unsigned v0 = ((const unsigned*)(xb + (size_t)q.x * DIN))[l];
        unsigned v1 = ((const unsigned*)(xb + (size_t)q.y * DIN))[l];
        unsigned v2 = ((const unsigned*)(xb + (size_t)q.z * DIN))[l];
        unsigned v3 = ((const unsigned*)(xb + (size_t)q.w * DIN))[l];
        s0 += bf16tof(v0 & 0xffffu) + bf16tof(v1 & 0xffffu) + bf16tof(v2 & 0xffffu) + bf16tof(v3 & 0xffffu);
        s1 += bf16tof(v0 >> 16) + bf16tof(v1 >> 16) + bf16tof(v2 >> 16) + bf16tof(v3 >> 16);
    }
    for (; i < cc; ++i) {
        int src = nl[i];
        unsigned v = ((const unsigned*)(xb + (size_t)src * DIN))[l];
        s0 += bf16tof(v & 0xffffu);
        s1 += bf16tof(v >> 16);
    }
    float rd = 1.0f / fmaxf((float)cn, 1.0f);
    unsigned o = (unsigned)bf16rne(s0 * rd) | ((unsigned)bf16rne(s1 * rd) << 16);
    ((unsigned*)(mb + (size_t)node * DIN))[l] = o;
}

// ===========================================================================
// Split-GEMM path (BMT2=128, wave tile 64x64, A+W panel-double-buffered).
// ===========================================================================
#define BMT2 128

__global__ __launch_bounds__(1024, 4) void gemm1_kernel(
    const ushort* __restrict__ xb, const ushort* __restrict__ mb,
    const ushort* __restrict__ W1L, const float* __restrict__ bl,
    ushort* __restrict__ Hb, int N) {
    __shared__ unsigned char sm[81920];
    const int t = threadIdx.x;
    const int l = t & 63, w = t >> 6;
    const int wm = w >> 3, wn = w & 7;
    const int lm = l & 15, ch = l >> 4;
    const int base = blockIdx.x * BMT2;

    if (t < 512) {
        int c = t >> 7, row = t & 127;
        int node = base + row; if (node >= N) node = N - 1;
        gld16(mb + (size_t)node * DIN + c * 8, sm + t * 16);
    }
    gld16(W1L + (size_t)t * 8,          sm + 16384 + t * 16);
    gld16(W1L + (size_t)(t + 1024) * 8, sm + 16384 + (t + 1024) * 16);
    __syncthreads();

    f32x4 acc[4][4];
    #pragma unroll
    for (int ct = 0; ct < 4; ++ct) {
        float bv = bl[wn * 64 + ct * 16 + lm];
        #pragma unroll
        for (int f = 0; f < 4; ++f) acc[f][ct] = (f32x4){bv, bv, bv, bv};
    }

    for (int p = 0; p < 8; ++p) {
        if (p < 7) {
            int nb = (p + 1) & 1;
            if (t < 512) {
                int c = t >> 7, row = t & 127;
                int node = base + row; if (node >= N) node = N - 1;
                int k0 = (p + 1) * 32 + c * 8;
                const ushort* src = (k0 < DIN) ? (mb + (size_t)node * DIN + k0)
                                               : (xb + (size_t)node * DIN + (k0 - DIN));
                gld16(src, sm + nb * 8192 + t * 16);
            }
            const ushort* wsrc = W1L + (size_t)(p + 1) * 16384;
            gld16(wsrc + (size_t)t * 8,          sm + 16384 + nb * 32768 + t * 16);
            gld16(wsrc + (size_t)(t + 1024) * 8, sm + 16384 + nb * 32768 + (t + 1024) * 16);
        }
        const unsigned ab = (p & 1) * 8192;
        const unsigned bb = 16384 + (p & 1) * 32768;
        short8 a[4], b[4];
        #pragma unroll
        for (int f = 0; f < 4; ++f)
            a[f] = *(const short8*)(sm + ab + (ch * 128 + wm * 64 + f * 16 + lm) * 16);
        #pragma unroll
        for (int ct = 0; ct < 4; ++ct)
            b[ct] = *(const short8*)(sm + bb + (ch * 512 + wn * 64 + ct * 16 + lm) * 16);
        #pragma unroll
        for (int f = 0; f < 4; ++f)
            #pragma unroll
            for (int ct = 0; ct < 4; ++ct)
                acc[f][ct] = __builtin_amdgcn_mfma_f32_16x16x32_bf16(a[f], b[ct], acc[f][ct], 0, 0, 0);
        __syncthreads();
    }

    #pragma unroll
    for (int f = 0; f < 4; ++f)
        #pragma unroll
        for (int ct = 0; ct < 4; ++ct) {
            int n = wn * 64 + ct * 16 + lm;
            #pragma unroll
            for (int r = 0; r < 4; ++r) {
                int m = wm * 64 + f * 16 + ch * 4 + r;
                int node = base + m;
                if (node < N) Hb[(size_t)node * HID + n] = bf16rne(fmaxf(acc[f][ct][r], 0.0f));
            }
        }
}

__global__ __launch_bounds__(1024, 4) void gemm2_kernel(
    const ushort* __restrict__ Hb, const ushort* __restrict__ W2L,
    const float* __restrict__ bp, float* __restrict__ out, int N) {
    __shared__ unsigned char sm[81920];
    const int t = threadIdx.x;
    const int l = t & 63, w = t >> 6;
    const int wm = w >> 3, wn = w & 7;
    const int lm = l & 15, ch = l >> 4;
    const int base = blockIdx.x * BMT2;

    if (t < 512) {
        int c = t >> 7, row = t & 127;
        int node = base + row; if (node >= N) node = N - 1;
        gld16(Hb + (size_t)node * HID + c * 8, sm + t * 16);
    }
    gld16(W2L + (size_t)t * 8,          sm + 16384 + t * 16);
    gld16(W2L + (size_t)(t + 1024) * 8, sm + 16384 + (t + 1024) * 16);
    __syncthreads();

    f32x4 d[4][4];
    #pragma unroll
    for (int ct = 0; ct < 4; ++ct) {
        float bv = bp[wn * 64 + ct * 16 + lm];
        #pragma unroll
        for (int f = 0; f < 4; ++f) d[f][ct] = (f32x4){bv, bv, bv, bv};
    }

    for (int q = 0; q < 16; ++q) {
        if (q < 15) {
            int nb = (q + 1) & 1;
            if (t < 512) {
                int c = t >> 7, row = t & 127;
                int node = base + row; if (node >= N) node = N - 1;
                gld16(Hb + (size_t)node * HID + (q + 1) * 32 + c * 8, sm + nb * 8192 + t * 16);
            }
            const ushort* wsrc = W2L + (size_t)(q + 1) * 16384;
            gld16(wsrc + (size_t)t * 8,          sm + 16384 + nb * 32768 + t * 16);
            gld16(wsrc + (size_t)(t + 1024) * 8, sm + 16384 + nb * 32768 + (t + 1024) * 16);
        }
        const unsigned ab = (q & 1) * 8192;
        const unsigned bb = 16384 + (q & 1) * 32768;
        short8 a[4], b[4];
        #pragma unroll
        for (int f = 0; f < 4; ++f)
            a[f] = *(const short8*)(sm + ab + (ch * 128 + wm * 64 + f * 16 + lm) * 16);
        #pragma unroll
        for (int ct = 0; ct < 4; ++ct)
            b[ct] = *(const short8*)(sm + bb + (ch * 512 + wn * 64 + ct * 16 + lm) * 16);
        #pragma unroll
        for (int f = 0; f < 4; ++f)
            #pragma unroll
            for (int ct = 0; ct < 4; ++ct)
                d[f][ct] = __builtin_amdgcn_mfma_f32_16x16x32_bf16(a[f], b[ct], d[f][ct], 0, 0, 0);
        __syncthreads();
    }

    #pragma unroll
    for (int f = 0; f < 4; ++f)
        #pragma unroll
        for (int ct = 0; ct < 4; ++ct) {
            int n = wn * 64 + ct * 16 + lm;
            #pragma unroll
            for (int r = 0; r < 4; ++r) {
                int m = wm * 64 + f * 16 + ch * 4 + r;
                int node = base + m;
                if (node < N) out[(size_t)node * HID + n] = d[f][ct][r];
            }
        }
}

// ===========================================================================
// Fallback: fused kernel (ws too small for split buffers)
// ===========================================================================
#define BMT 64
__global__ __launch_bounds__(1024, 4) void gemm_fused_kernel(
    const ushort* __restrict__ xb, const ushort* __restrict__ mb,
    const ushort* __restrict__ W1L, const ushort* __restrict__ W2L,
    const float* __restrict__ bl, const float* __restrict__ bp,
    float* __restrict__ out, int N) {
    __shared__ unsigned char sm[131072];
    const int t = threadIdx.x;
    const int l = t & 63;
    const int w = t >> 6;
    const int wm = w >> 3;
    const int wn = w & 7;
    const int lm = l & 15;
    const int ch = l >> 4;
    const int base = blockIdx.x * BMT;

    #pragma unroll
    for (int j = 0; j < 2; ++j) {
        int idx = w * 128 + j * 64 + l;
        int p = idx >> 8, c = (idx >> 6) & 3, row = idx & 63;
        int node = base + row;
        if (node >= N) node = N - 1;
        int k0 = p * 32 + c * 8;
        const ushort* src = (k0 < DIN) ? (mb + (size_t)node * DIN + k0)
                                       : (xb + (size_t)node * DIN + (k0 - DIN));
        gld16(src, sm + idx * 16);
    }
    #pragma unroll
    for (int j = 0; j < 2; ++j) {
        int ci = w * 128 + j * 64 + l;
        gld16(W1L + (size_t)ci * 8, sm + 32768 + ci * 16);
    }
    __syncthreads();

    f32x4 acc[2][4];
    #pragma unroll
    for (int ct = 0; ct < 4; ++ct) {
        float bv = bl[wn * 64 + ct * 16 + lm];
        acc[0][ct] = (f32x4){bv, bv, bv, bv};
        acc[1][ct] = acc[0][ct];
    }
    for (int p = 0; p < 8; ++p) {
        if (p < 7) {
            const ushort* wsrc = W1L + (size_t)(p + 1) * 16384;
            unsigned boff = 32768 + (((p + 1) & 1) << 15);
            #pragma unroll
            for (int j = 0; j < 2; ++j) {
                int ci = w * 128 + j * 64 + l;
                gld16(wsrc + (size_t)ci * 8, sm + boff + ci * 16);
            }
        }
        const unsigned abase = (p * 256 + ch * 64) * 16;
        const unsigned bbase = 32768 + ((p & 1) << 15) + ch * 8192;
        short8 a[2], b[4];
        #pragma unroll
        for (int f = 0; f < 2; ++f)
            a[f] = *(const short8*)(sm + abase + (wm * 32 + f * 16 + lm) * 16);
        #pragma unroll
        for (int ct = 0; ct < 4; ++ct)
            b[ct] = *(const short8*)(sm + bbase + (wn * 64 + ct * 16 + lm) * 16);
        #pragma unroll
        for (int f = 0; f < 2; ++f)
            #pragma unroll
            for (int ct = 0; ct < 4; ++ct)
                acc[f][ct] = __builtin_amdgcn_mfma_f32_16x16x32_bf16(a[f], b[ct], acc[f][ct], 0, 0, 0);
        __syncthreads();
    }

    #pragma unroll
    for (int j = 0; j < 2; ++j) {
        int ci = w * 128 + j * 64 + l;
        gld16(W2L + (size_t)ci * 8, sm + 65536 + ci * 16);
    }
    #pragma unroll
    for (int f = 0; f < 2; ++f)
        #pragma unroll
        for (int ct = 0; ct < 4; ++ct) {
            int n = wn * 64 + ct * 16 + lm;
            unsigned hb = ((n >> 5) * 256 + ((n >> 3) & 3) * 64) * 16 + (n & 7) * 2;
            #pragma unroll
            for (int r = 0; r < 4; ++r) {
                int m = wm * 32 + f * 16 + ch * 4 + r;
                *(ushort*)(sm + hb + m * 16) = bf16rne(fmaxf(acc[f][ct][r], 0.0f));
            }
        }
    __syncthreads();

    f32x4 d[2][4];
    #pragma unroll
    for (int ct = 0; ct < 4; ++ct) {
        float bv = bp[wn * 64 + ct * 16 + lm];
        d[0][ct] = (f32x4){bv, bv, bv, bv};
        d[1][ct] = d[0][ct];
    }
    for (int q = 0; q < 16; ++q) {
        if (q < 15) {
            const ushort* wsrc = W2L + (size_t)(q + 1) * 16384;
            unsigned boff = 65536 + (((q + 1) & 1) << 15);
            #pragma unroll
            for (int j = 0; j < 2; ++j) {
                int ci = w * 128 + j * 64 + l;
                gld16(wsrc + (size_t)ci * 8, sm + boff + ci * 16);
            }
        }
        const unsigned abase = (q * 256 + ch * 64) * 16;
        const unsigned bbase = 65536 + ((q & 1) << 15) + ch * 8192;
        short8 a[2], b[4];
        #pragma unroll
        for (int f = 0; f < 2; ++f)
            a[f] = *(const short8*)(sm + abase + (wm * 32 + f * 16 + lm) * 16);
        #pragma unroll
        for (int ct = 0; ct < 4; ++ct)
            b[ct] = *(const short8*)(sm + bbase + (wn * 64 + ct * 16 + lm) * 16);
        #pragma unroll
        for (int f = 0; f < 2; ++f)
            #pragma unroll
            for (int ct = 0; ct < 4; ++ct)
                d[f][ct] = __builtin_amdgcn_mfma_f32_16x16x32_bf16(a[f], b[ct], d[f][ct], 0, 0, 0);
        __syncthreads();
    }

    #pragma unroll
    for (int f = 0; f < 2; ++f)
        #pragma unroll
        for (int ct = 0; ct < 4; ++ct) {
            int n = wn * 64 + ct * 16 + lm;
            #pragma unroll
            for (int r = 0; r < 4; ++r) {
                int m = wm * 32 + f * 16 + ch * 4 + r;
                int node = base + m;
                if (node < N) out[(size_t)node * HID + n] = d[f][ct][r];
            }
        }
}

extern "C" void kernel_launch(void* const* d_in, const int* in_sizes, int n_in,
                              void* d_out, int out_size, void* d_ws, size_t ws_size,
                              hipStream_t stream) {
    const float* x  = (const float*)d_in[0];
    const int*   ei = (const int*)d_in[1];
    const float* Wl = (const float*)d_in[2];
    const float* bl = (const float*)d_in[3];
    const float* Wr = (const float*)d_in[4];
    const float* Wp = (const float*)d_in[5];
    const float* bp = (const float*)d_in[6];
    float* out = (float*)d_out;

    const int N = in_sizes[0] / DIN;
    const int E = in_sizes[1] / 2;
    const int NB = (N + 255) >> BSH;                                  // 391 buckets

    const size_t hBytes  = (size_t)N * HID * sizeof(ushort);          // 102.4 MB
    const size_t xbBytes = (size_t)N * DIN * sizeof(ushort);          // 25.6 MB
    const size_t w1Bytes = 131072 * sizeof(ushort);
    const size_t w2Bytes = 262144 * sizeof(ushort);
    const size_t bucketBytes = ((size_t)NB << CAPSH) * sizeof(unsigned) + NB * sizeof(int);
    const size_t needBig = hBytes + 2 * xbBytes + w1Bytes + w2Bytes;  // ~154.4 MB

    // pack needs src < 2^24; dloc 8 bits; guard (N=100000 << 2^24 OK)
    if (ws_size >= needBig && bucketBytes <= hBytes && N < (1 << 24)) {
        char* base = (char*)d_ws;
        // bucket scratch overlays the Hb region (dead before gemm1)
        unsigned* eb  = (unsigned*)base;                  // NB<<CAPSH u32
        int*      bcur = (int*)(eb + ((size_t)NB << CAPSH));
        ushort* Hb   = (ushort*)base;
        ushort* xb   = (ushort*)(base + hBytes);
        ushort* mb   = (ushort*)(base + hBytes + xbBytes);
        ushort* W1L  = (ushort*)(base + hBytes + 2 * xbBytes);
        ushort* W2L  = (ushort*)((char*)W1L + w1Bytes);

        prep_w<<<192, 256, 0, stream>>>(Wl, Wr, Wp, W1L, W2L);
        xcvt<<<((N * DIN / 4) + 255) / 256, 256, 0, stream>>>(x, xb, N * DIN / 4);
        binit_kernel<<<(NB + 1023) / 1024, 1024, 0, stream>>>(bcur, NB);
        bucket_kernel<<<(E + EPB - 1) / EPB, 256, 0, stream>>>(ei, bcur, eb, E, NB);
        agg3_kernel<<<NB, 512, 0, stream>>>(xb, eb, bcur, mb, N);
        int g = (N + BMT2 - 1) / BMT2;
        gemm1_kernel<<<g, 1024, 0, stream>>>(xb, mb, W1L, bl, Hb, N);
        gemm2_kernel<<<g, 1024, 0, stream>>>(Hb, W2L, bp, out, N);
    } else {
        int*    cnt = (int*)d_ws;
        int*    nbr = cnt + N;
        ushort* xb  = (ushort*)(nbr + (size_t)N * NPAD);
        ushort* mb  = xb + (size_t)N * DIN;
        ushort* W1L = mb + (size_t)N * DIN;
        ushort* W2L = W1L + 131072;

        hipMemsetAsync(cnt, 0, (size_t)N * sizeof(int), stream);
        prep_w<<<192, 256, 0, stream>>>(Wl, Wr, Wp, W1L, W2L);
        xcvt<<<((N * DIN / 4) + 255) / 256, 256, 0, stream>>>(x, xb, N * DIN / 4);
        fill_kernel<<<(E + 255) / 256, 256, 0, stream>>>(ei, cnt, nbr, E);
        agg_kernel<<<(N + 3) / 4, 256, 0, stream>>>(xb, cnt, nbr, mb, N);
        gemm_fused_kernel<<<(N + BMT - 1) / BMT, 1024, 0, stream>>>(xb, mb, W1L, W2L, bl, bp, out, N);
    }
}

// Round 17
// 275.060 us; speedup vs baseline: 5.7449x; 1.0352x over previous
//
#include <hip/hip_runtime.h>
#include <hip/hip_bf16.h>

#define DIN  128
#define HID  512
#define K1   256
#define NPAD 96       // fallback path only
#define BSH  8        // bucket = 256 dst nodes
#define CAPSH 13      // bucket capacity 8192 (mean 4081, ~64-sigma safe)
#define EPB  4096     // edges per bucket_kernel block

typedef __attribute__((ext_vector_type(8))) short short8;
typedef __attribute__((ext_vector_type(4))) float f32x4;

__device__ inline ushort bf16rne(float f) {
    union { float f; unsigned u; } c; c.f = f;
    unsigned b = c.u + 0x7fff + ((c.u >> 16) & 1);
    return (ushort)(b >> 16);
}
__device__ inline float bf16tof(unsigned lo16) {
    union { unsigned u; float f; } c; c.u = lo16 << 16;
    return c.f;
}
__device__ __forceinline__ void gld16(const void* g, void* l) {
    __builtin_amdgcn_global_load_lds((const __attribute__((address_space(1))) unsigned int*)g,
                                     (__attribute__((address_space(3))) unsigned int*)l, 16, 0, 0);
}

// ---------------------------------------------------------------------------
// weights -> bf16 panelized LDS-image layout
// ---------------------------------------------------------------------------
__global__ void prep_w(const float* __restrict__ Wl, const float* __restrict__ Wr,
                       const float* __restrict__ Wp,
                       ushort* __restrict__ W1L, ushort* __restrict__ W2L) {
    int t = blockIdx.x * blockDim.x + threadIdx.x;
    if (t < 8 * 4 * 512) {
        int p = t >> 11, c = (t >> 9) & 3, col = t & 511;
        int k0 = p * 32 + c * 8;
        #pragma unroll
        for (int r = 0; r < 8; ++r) {
            int k = k0 + r;
            float v = (k < DIN) ? Wl[k * HID + col] : Wr[(k - DIN) * HID + col];
            W1L[(size_t)t * 8 + r] = bf16rne(v);
        }
    } else if (t < 8 * 4 * 512 + 16 * 4 * 512) {
        int t2 = t - 8 * 4 * 512;
        int p = t2 >> 11, c = (t2 >> 9) & 3, col = t2 & 511;
        int k0 = p * 32 + c * 8;
        #pragma unroll
        for (int r = 0; r < 8; ++r)
            W2L[(size_t)t2 * 8 + r] = bf16rne(Wp[(k0 + r) * HID + col]);
    }
}

__global__ void xcvt(const float* __restrict__ x, ushort* __restrict__ xb, int total4) {
    int i = blockIdx.x * blockDim.x + threadIdx.x;
    if (i >= total4) return;
    const float4 v = ((const float4*)x)[i];
    ushort4 o;
    o.x = bf16rne(v.x); o.y = bf16rne(v.y); o.z = bf16rne(v.z); o.w = bf16rne(v.w);
    ((ushort4*)xb)[i] = o;
}

// ---------------------------------------------------------------------------
// bucket pass: edges -> (dst>>8)-bucketed packed u32 (src<<8 | dst&255).
// ---------------------------------------------------------------------------
__global__ void binit_kernel(int* __restrict__ bcur, int nb) {
    int i = threadIdx.x + blockIdx.x * 1024;
    if (i < nb) bcur[i] = i << CAPSH;
}

__global__ __launch_bounds__(256) void bucket_kernel(
    const int* __restrict__ ei, int* __restrict__ bcur,
    unsigned* __restrict__ eb, int E, int nb) {
    __shared__ int lhist[400], lbase[400], lcur[400];
    const int t = threadIdx.x;
    for (int i = t; i < nb; i += 256) lhist[i] = 0;
    __syncthreads();
    const int e0 = blockIdx.x * EPB;
    int srcs[16], dsts[16], bs[16];
    #pragma unroll
    for (int i = 0; i < 16; ++i) {
        int e = e0 + i * 256 + t;
        if (e < E) {
            srcs[i] = ei[e];
            dsts[i] = ei[E + e];
            bs[i] = dsts[i] >> BSH;
            atomicAdd(&lhist[bs[i]], 1);
        } else bs[i] = -1;
    }
    __syncthreads();
    for (int i = t; i < nb; i += 256) {
        lcur[i] = 0;
        if (lhist[i] > 0) lbase[i] = atomicAdd(&bcur[i], lhist[i]);
    }
    __syncthreads();
    #pragma unroll
    for (int i = 0; i < 16; ++i) {
        if (bs[i] >= 0) {
            int off = atomicAdd(&lcur[bs[i]], 1);
            int p = lbase[bs[i]] + off;
            if (p < ((bs[i] + 1) << CAPSH))
                eb[p] = ((unsigned)srcs[i] << 8) | (unsigned)(dsts[i] & 255);
        }
    }
}

// ---------------------------------------------------------------------------
// agg3: one block per 256-node bucket, 1024 threads = 16 waves (2 blocks/CU
// = 32 waves/CU for gather-latency TLP). LDS counting sort (hist -> scan ->
// scatter) builds per-node src lists in LDS, then wave-per-node gather with
// a 16/8/4/1 batch ladder keeping up to 16 gathers in flight.
// ---------------------------------------------------------------------------
__global__ __launch_bounds__(1024) void agg3_kernel(
    const ushort* __restrict__ xb, const unsigned* __restrict__ eb,
    const int* __restrict__ bcur, ushort* __restrict__ mb, int N) {
    __shared__ int sLDS[1 << CAPSH];          // sorted src list (32KB)
    __shared__ int pcnt[256], tmp[256], poff[256], pcur[256];
    const int t = threadIdx.x;
    const int l = t & 63;
    const int wv = t >> 6;                    // 0..15
    const int b = blockIdx.x;

    if (t < 256) pcnt[t] = 0;
    __syncthreads();

    const int vbase = b << CAPSH;
    int valid = bcur[b] - vbase;
    if (valid > (1 << CAPSH)) valid = 1 << CAPSH;

    // pass 1: histogram
    for (int i = t; i < valid; i += 1024)
        atomicAdd(&pcnt[eb[vbase + i] & 255u], 1);
    __syncthreads();

    // Hillis-Steele inclusive scan over 256 counts
    if (t < 256) tmp[t] = pcnt[t];
    __syncthreads();
    #pragma unroll
    for (int s = 1; s < 256; s <<= 1) {
        int v = 0;
        if (t < 256) { v = tmp[t]; if (t >= s) v += tmp[t - s]; }
        __syncthreads();
        if (t < 256) tmp[t] = v;
        __syncthreads();
    }
    if (t < 256) { poff[t] = tmp[t] - pcnt[t]; pcur[t] = tmp[t] - pcnt[t]; }
    __syncthreads();

    // pass 2: scatter srcs into sorted order
    for (int i = t; i < valid; i += 1024) {
        unsigned u = eb[vbase + i];
        int slot = atomicAdd(&pcur[u & 255u], 1);
        sLDS[slot] = (int)(u >> 8);
    }
    __syncthreads();

    // gather-mean: wave per node, 16/8/4/1 in-flight gather ladder
    for (int nl = wv; nl < 256; nl += 16) {
        int node = (b << BSH) + nl;
        if (node >= N) continue;
        int cn = pcnt[nl];
        const int off = poff[nl];
        float s0 = 0.f, s1 = 0.f;
        int i = 0;
        for (; i + 16 <= cn; i += 16) {
            int s_[16];
            #pragma unroll
            for (int j = 0; j < 16; ++j) s_[j] = sLDS[off + i + j];   // broadcast
            unsigned v_[16];
            #pragma unroll
            for (int j = 0; j < 16; ++j)
                v_[j] = ((const unsigned*)(xb + (size_t)s_[j] * DIN))[l];
            #pragma unroll
            for (int j = 0; j < 16; ++j) {
                s0 += bf16tof(v_[j] & 0xffffu);
                s1 += bf16tof(v_[j] >> 16);
            }
        }
        for (; i + 8 <= cn; i += 8) {
            int s_[8];
            #pragma unroll
            for (int j = 0; j < 8; ++j) s_[j] = sLDS[off + i + j];
            unsigned v_[8];
            #pragma unroll
            for (int j = 0; j < 8; ++j)
                v_[j] = ((const unsigned*)(xb + (size_t)s_[j] * DIN))[l];
            #pragma unroll
            for (int j = 0; j < 8; ++j) {
                s0 += bf16tof(v_[j] & 0xffffu);
                s1 += bf16tof(v_[j] >> 16);
            }
        }
        for (; i + 4 <= cn; i += 4) {
            int s_[4];
            #pragma unroll
            for (int j = 0; j < 4; ++j) s_[j] = sLDS[off + i + j];
            unsigned v_[4];
            #pragma unroll
            for (int j = 0; j < 4; ++j)
                v_[j] = ((const unsigned*)(xb + (size_t)s_[j] * DIN))[l];
            #pragma unroll
            for (int j = 0; j < 4; ++j) {
                s0 += bf16tof(v_[j] & 0xffffu);
                s1 += bf16tof(v_[j] >> 16);
            }
        }
        for (; i < cn; ++i) {
            int src = sLDS[off + i];
            unsigned v = ((const unsigned*)(xb + (size_t)src * DIN))[l];
            s0 += bf16tof(v & 0xffffu);
            s1 += bf16tof(v >> 16);
        }
        float rd = 1.0f / fmaxf((float)cn, 1.0f);
        unsigned o = (unsigned)bf16rne(s0 * rd) | ((unsigned)bf16rne(s1 * rd) << 16);
        ((unsigned*)(mb + (size_t)node * DIN))[l] = o;
    }
}

// ---------------------------------------------------------------------------
// fallback-path fill + gather-mean (unbucketed, uses nbr lists)
// ---------------------------------------------------------------------------
__global__ void fill_kernel(const int* __restrict__ ei, int* __restrict__ cnt,
                            int* __restrict__ nbr, int E) {
    int e = blockIdx.x * blockDim.x + threadIdx.x;
    if (e >= E) return;
    int src = ei[e];
    int dst = ei[E + e];
    int pos = atomicAdd(cnt + dst, 1);
    if (pos < NPAD) nbr[(size_t)dst * NPAD + pos] = src;
}

__global__ __launch_bounds__(256) void agg_kernel(
    const ushort* __restrict__ xb, const int* __restrict__ cnt, const int* __restrict__ nbr,
    ushort* __restrict__ mb, int N) {
    int node = blockIdx.x * 4 + (threadIdx.x >> 6);
    if (node >= N) return;
    int l = threadIdx.x & 63;
    int cn = cnt[node];
    int cc = cn < NPAD ? cn : NPAD;
    const int* nl = nbr + (size_t)node * NPAD;
    float s0 = 0.f, s1 = 0.f;
    int i = 0;
    for (; i + 4 <= cc; i += 4) {
        int4 q = *(const int4*)(nl + i);
        unsigned v0 = ((const unsigned*)(xb + (size_t)q.x * DIN))[l];
        unsigned v1 = ((const unsigned*)(xb + (size_t)q.y * DIN))[l];
        unsigned v2 = ((const unsigned*)(xb + (size_t)q.z * DIN))[l];
        unsigned v3 = ((const unsigned*)(xb + (size_t)q.w * DIN))[l];
        s0 += bf16tof(v0 & 0xffffu) + bf16tof(v1 & 0xffffu) + bf16tof(v2 & 0xffffu) + bf16tof(v3 & 0xffffu);
        s1 += bf16tof(v0 >> 16) + bf16tof(v1 >> 16) + bf16tof(v2 >> 16) + bf16tof(v3 >> 16);
    }
    for (; i < cc; ++i) {
        int src = nl[i];
        unsigned v = ((const unsigned*)(xb + (size_t)src * DIN))[l];
        s0 += bf16tof(v & 0xffffu);
        s1 += bf16tof(v >> 16);
    }
    float rd = 1.0f / fmaxf((float)cn, 1.0f);
    unsigned o = (unsigned)bf16rne(s0 * rd) | ((unsigned)bf16rne(s1 * rd) << 16);
    ((unsigned*)(mb + (size_t)node * DIN))[l] = o;
}

// ===========================================================================
// Split-GEMM path (BMT2=128, wave tile 64x64, A+W panel-double-buffered).
// ===========================================================================
#define BMT2 128

__global__ __launch_bounds__(1024, 4) void gemm1_kernel(
    const ushort* __restrict__ xb, const ushort* __restrict__ mb,
    const ushort* __restrict__ W1L, const float* __restrict__ bl,
    ushort* __restrict__ Hb, int N) {
    __shared__ unsigned char sm[81920];
    const int t = threadIdx.x;
    const int l = t & 63, w = t >> 6;
    const int wm = w >> 3, wn = w & 7;
    const int lm = l & 15, ch = l >> 4;
    const int base = blockIdx.x * BMT2;

    if (t < 512) {
        int c = t >> 7, row = t & 127;
        int node = base + row; if (node >= N) node = N - 1;
        gld16(mb + (size_t)node * DIN + c * 8, sm + t * 16);
    }
    gld16(W1L + (size_t)t * 8,          sm + 16384 + t * 16);
    gld16(W1L + (size_t)(t + 1024) * 8, sm + 16384 + (t + 1024) * 16);
    __syncthreads();

    f32x4 acc[4][4];
    #pragma unroll
    for (int ct = 0; ct < 4; ++ct) {
        float bv = bl[wn * 64 + ct * 16 + lm];
        #pragma unroll
        for (int f = 0; f < 4; ++f) acc[f][ct] = (f32x4){bv, bv, bv, bv};
    }

    for (int p = 0; p < 8; ++p) {
        if (p < 7) {
            int nb = (p + 1) & 1;
            if (t < 512) {
                int c = t >> 7, row = t & 127;
                int node = base + row; if (node >= N) node = N - 1;
                int k0 = (p + 1) * 32 + c * 8;
                const ushort* src = (k0 < DIN) ? (mb + (size_t)node * DIN + k0)
                                               : (xb + (size_t)node * DIN + (k0 - DIN));
                gld16(src, sm + nb * 8192 + t * 16);
            }
            const ushort* wsrc = W1L + (size_t)(p + 1) * 16384;
            gld16(wsrc + (size_t)t * 8,          sm + 16384 + nb * 32768 + t * 16);
            gld16(wsrc + (size_t)(t + 1024) * 8, sm + 16384 + nb * 32768 + (t + 1024) * 16);
        }
        const unsigned ab = (p & 1) * 8192;
        const unsigned bb = 16384 + (p & 1) * 32768;
        short8 a[4], b[4];
        #pragma unroll
        for (int f = 0; f < 4; ++f)
            a[f] = *(const short8*)(sm + ab + (ch * 128 + wm * 64 + f * 16 + lm) * 16);
        #pragma unroll
        for (int ct = 0; ct < 4; ++ct)
            b[ct] = *(const short8*)(sm + bb + (ch * 512 + wn * 64 + ct * 16 + lm) * 16);
        #pragma unroll
        for (int f = 0; f < 4; ++f)
            #pragma unroll
            for (int ct = 0; ct < 4; ++ct)
                acc[f][ct] = __builtin_amdgcn_mfma_f32_16x16x32_bf16(a[f], b[ct], acc[f][ct], 0, 0, 0);
        __syncthreads();
    }

    #pragma unroll
    for (int f = 0; f < 4; ++f)
        #pragma unroll
        for (int ct = 0; ct < 4; ++ct) {
            int n = wn * 64 + ct * 16 + lm;
            #pragma unroll
            for (int r = 0; r < 4; ++r) {
                int m = wm * 64 + f * 16 + ch * 4 + r;
                int node = base + m;
                if (node < N) Hb[(size_t)node * HID + n] = bf16rne(fmaxf(acc[f][ct][r], 0.0f));
            }
        }
}

__global__ __launch_bounds__(1024, 4) void gemm2_kernel(
    const ushort* __restrict__ Hb, const ushort* __restrict__ W2L,
    const float* __restrict__ bp, float* __restrict__ out, int N) {
    __shared__ unsigned char sm[81920];
    const int t = threadIdx.x;
    const int l = t & 63, w = t >> 6;
    const int wm = w >> 3, wn = w & 7;
    const int lm = l & 15, ch = l >> 4;
    const int base = blockIdx.x * BMT2;

    if (t < 512) {
        int c = t >> 7, row = t & 127;
        int node = base + row; if (node >= N) node = N - 1;
        gld16(Hb + (size_t)node * HID + c * 8, sm + t * 16);
    }
    gld16(W2L + (size_t)t * 8,          sm + 16384 + t * 16);
    gld16(W2L + (size_t)(t + 1024) * 8, sm + 16384 + (t + 1024) * 16);
    __syncthreads();

    f32x4 d[4][4];
    #pragma unroll
    for (int ct = 0; ct < 4; ++ct) {
        float bv = bp[wn * 64 + ct * 16 + lm];
        #pragma unroll
        for (int f = 0; f < 4; ++f) d[f][ct] = (f32x4){bv, bv, bv, bv};
    }

    for (int q = 0; q < 16; ++q) {
        if (q < 15) {
            int nb = (q + 1) & 1;
            if (t < 512) {
                int c = t >> 7, row = t & 127;
                int node = base + row; if (node >= N) node = N - 1;
                gld16(Hb + (size_t)node * HID + (q + 1) * 32 + c * 8, sm + nb * 8192 + t * 16);
            }
            const ushort* wsrc = W2L + (size_t)(q + 1) * 16384;
            gld16(wsrc + (size_t)t * 8,          sm + 16384 + nb * 32768 + t * 16);
            gld16(wsrc + (size_t)(t + 1024) * 8, sm + 16384 + nb * 32768 + (t + 1024) * 16);
        }
        const unsigned ab = (q & 1) * 8192;
        const unsigned bb = 16384 + (q & 1) * 32768;
        short8 a[4], b[4];
        #pragma unroll
        for (int f = 0; f < 4; ++f)
            a[f] = *(const short8*)(sm + ab + (ch * 128 + wm * 64 + f * 16 + lm) * 16);
        #pragma unroll
        for (int ct = 0; ct < 4; ++ct)
            b[ct] = *(const short8*)(sm + bb + (ch * 512 + wn * 64 + ct * 16 + lm) * 16);
        #pragma unroll
        for (int f = 0; f < 4; ++f)
            #pragma unroll
            for (int ct = 0; ct < 4; ++ct)
                d[f][ct] = __builtin_amdgcn_mfma_f32_16x16x32_bf16(a[f], b[ct], d[f][ct], 0, 0, 0);
        __syncthreads();
    }

    #pragma unroll
    for (int f = 0; f < 4; ++f)
        #pragma unroll
        for (int ct = 0; ct < 4; ++ct) {
            int n = wn * 64 + ct * 16 + lm;
            #pragma unroll
            for (int r = 0; r < 4; ++r) {
                int m = wm * 64 + f * 16 + ch * 4 + r;
                int node = base + m;
                if (node < N) out[(size_t)node * HID + n] = d[f][ct][r];
            }
        }
}

// ===========================================================================
// Fallback: fused kernel (ws too small for split buffers)
// ===========================================================================
#define BMT 64
__global__ __launch_bounds__(1024, 4) void gemm_fused_kernel(
    const ushort* __restrict__ xb, const ushort* __restrict__ mb,
    const ushort* __restrict__ W1L, const ushort* __restrict__ W2L,
    const float* __restrict__ bl, const float* __restrict__ bp,
    float* __restrict__ out, int N) {
    __shared__ unsigned char sm[131072];
    const int t = threadIdx.x;
    const int l = t & 63;
    const int w = t >> 6;
    const int wm = w >> 3;
    const int wn = w & 7;
    const int lm = l & 15;
    const int ch = l >> 4;
    const int base = blockIdx.x * BMT;

    #pragma unroll
    for (int j = 0; j < 2; ++j) {
        int idx = w * 128 + j * 64 + l;
        int p = idx >> 8, c = (idx >> 6) & 3, row = idx & 63;
        int node = base + row;
        if (node >= N) node = N - 1;
        int k0 = p * 32 + c * 8;
        const ushort* src = (k0 < DIN) ? (mb + (size_t)node * DIN + k0)
                                       : (xb + (size_t)node * DIN + (k0 - DIN));
        gld16(src, sm + idx * 16);
    }
    #pragma unroll
    for (int j = 0; j < 2; ++j) {
        int ci = w * 128 + j * 64 + l;
        gld16(W1L + (size_t)ci * 8, sm + 32768 + ci * 16);
    }
    __syncthreads();

    f32x4 acc[2][4];
    #pragma unroll
    for (int ct = 0; ct < 4; ++ct) {
        float bv = bl[wn * 64 + ct * 16 + lm];
        acc[0][ct] = (f32x4){bv, bv, bv, bv};
        acc[1][ct] = acc[0][ct];
    }
    for (int p = 0; p < 8; ++p) {
        if (p < 7) {
            const ushort* wsrc = W1L + (size_t)(p + 1) * 16384;
            unsigned boff = 32768 + (((p + 1) & 1) << 15);
            #pragma unroll
            for (int j = 0; j < 2; ++j) {
                int ci = w * 128 + j * 64 + l;
                gld16(wsrc + (size_t)ci * 8, sm + boff + ci * 16);
            }
        }
        const unsigned abase = (p * 256 + ch * 64) * 16;
        const unsigned bbase = 32768 + ((p & 1) << 15) + ch * 8192;
        short8 a[2], b[4];
        #pragma unroll
        for (int f = 0; f < 2; ++f)
            a[f] = *(const short8*)(sm + abase + (wm * 32 + f * 16 + lm) * 16);
        #pragma unroll
        for (int ct = 0; ct < 4; ++ct)
            b[ct] = *(const short8*)(sm + bbase + (wn * 64 + ct * 16 + lm) * 16);
        #pragma unroll
        for (int f = 0; f < 2; ++f)
            #pragma unroll
            for (int ct = 0; ct < 4; ++ct)
                acc[f][ct] = __builtin_amdgcn_mfma_f32_16x16x32_bf16(a[f], b[ct], acc[f][ct], 0, 0, 0);
        __syncthreads();
    }

    #pragma unroll
    for (int j = 0; j < 2; ++j) {
        int ci = w * 128 + j * 64 + l;
        gld16(W2L + (size_t)ci * 8, sm + 65536 + ci * 16);
    }
    #pragma unroll
    for (int f = 0; f < 2; ++f)
        #pragma unroll
        for (int ct = 0; ct < 4; ++ct) {
            int n = wn * 64 + ct * 16 + lm;
            unsigned hb = ((n >> 5) * 256 + ((n >> 3) & 3) * 64) * 16 + (n & 7) * 2;
            #pragma unroll
            for (int r = 0; r < 4; ++r) {
                int m = wm * 32 + f * 16 + ch * 4 + r;
                *(ushort*)(sm + hb + m * 16) = bf16rne(fmaxf(acc[f][ct][r], 0.0f));
            }
        }
    __syncthreads();

    f32x4 d[2][4];
    #pragma unroll
    for (int ct = 0; ct < 4; ++ct) {
        float bv = bp[wn * 64 + ct * 16 + lm];
        d[0][ct] = (f32x4){bv, bv, bv, bv};
        d[1][ct] = d[0][ct];
    }
    for (int q = 0; q < 16; ++q) {
        if (q < 15) {
            const ushort* wsrc = W2L + (size_t)(q + 1) * 16384;
            unsigned boff = 65536 + (((q + 1) & 1) << 15);
            #pragma unroll
            for (int j = 0; j < 2; ++j) {
                int ci = w * 128 + j * 64 + l;
                gld16(wsrc + (size_t)ci * 8, sm + boff + ci * 16);
            }
        }
        const unsigned abase = (q * 256 + ch * 64) * 16;
        const unsigned bbase = 65536 + ((q & 1) << 15) + ch * 8192;
        short8 a[2], b[4];
        #pragma unroll
        for (int f = 0; f < 2; ++f)
            a[f] = *(const short8*)(sm + abase + (wm * 32 + f * 16 + lm) * 16);
        #pragma unroll
        for (int ct = 0; ct < 4; ++ct)
            b[ct] = *(const short8*)(sm + bbase + (wn * 64 + ct * 16 + lm) * 16);
        #pragma unroll
        for (int f = 0; f < 2; ++f)
            #pragma unroll
            for (int ct = 0; ct < 4; ++ct)
                d[f][ct] = __builtin_amdgcn_mfma_f32_16x16x32_bf16(a[f], b[ct], d[f][ct], 0, 0, 0);
        __syncthreads();
    }

    #pragma unroll
    for (int f = 0; f < 2; ++f)
        #pragma unroll
        for (int ct = 0; ct < 4; ++ct) {
            int n = wn * 64 + ct * 16 + lm;
            #pragma unroll
            for (int r = 0; r < 4; ++r) {
                int m = wm * 32 + f * 16 + ch * 4 + r;
                int node = base + m;
                if (node < N) out[(size_t)node * HID + n] = d[f][ct][r];
            }
        }
}

extern "C" void kernel_launch(void* const* d_in, const int* in_sizes, int n_in,
                              void* d_out, int out_size, void* d_ws, size_t ws_size,
                              hipStream_t stream) {
    const float* x  = (const float*)d_in[0];
    const int*   ei = (const int*)d_in[1];
    const float* Wl = (const float*)d_in[2];
    const float* bl = (const float*)d_in[3];
    const float* Wr = (const float*)d_in[4];
    const float* Wp = (const float*)d_in[5];
    const float* bp = (const float*)d_in[6];
    float* out = (float*)d_out;

    const int N = in_sizes[0] / DIN;
    const int E = in_sizes[1] / 2;
    const int NB = (N + 255) >> BSH;                                  // 391 buckets

    const size_t hBytes  = (size_t)N * HID * sizeof(ushort);          // 102.4 MB
    const size_t xbBytes = (size_t)N * DIN * sizeof(ushort);          // 25.6 MB
    const size_t w1Bytes = 131072 * sizeof(ushort);
    const size_t w2Bytes = 262144 * sizeof(ushort);
    const size_t bucketBytes = ((size_t)NB << CAPSH) * sizeof(unsigned) + NB * sizeof(int);
    const size_t needBig = hBytes + 2 * xbBytes + w1Bytes + w2Bytes;  // ~154.4 MB

    if (ws_size >= needBig && bucketBytes <= hBytes && N < (1 << 24)) {
        char* base = (char*)d_ws;
        // bucket scratch overlays the Hb region (dead before gemm1)
        unsigned* eb  = (unsigned*)base;                  // NB<<CAPSH u32
        int*      bcur = (int*)(eb + ((size_t)NB << CAPSH));
        ushort* Hb   = (ushort*)base;
        ushort* xb   = (ushort*)(base + hBytes);
        ushort* mb   = (ushort*)(base + hBytes + xbBytes);
        ushort* W1L  = (ushort*)(base + hBytes + 2 * xbBytes);
        ushort* W2L  = (ushort*)((char*)W1L + w1Bytes);

        prep_w<<<192, 256, 0, stream>>>(Wl, Wr, Wp, W1L, W2L);
        xcvt<<<((N * DIN / 4) + 255) / 256, 256, 0, stream>>>(x, xb, N * DIN / 4);
        binit_kernel<<<(NB + 1023) / 1024, 1024, 0, stream>>>(bcur, NB);
        bucket_kernel<<<(E + EPB - 1) / EPB, 256, 0, stream>>>(ei, bcur, eb, E, NB);
        agg3_kernel<<<NB, 1024, 0, stream>>>(xb, eb, bcur, mb, N);
        int g = (N + BMT2 - 1) / BMT2;
        gemm1_kernel<<<g, 1024, 0, stream>>>(xb, mb, W1L, bl, Hb, N);
        gemm2_kernel<<<g, 1024, 0, stream>>>(Hb, W2L, bp, out, N);
    } else {
        int*    cnt = (int*)d_ws;
        int*    nbr = cnt + N;
        ushort* xb  = (ushort*)(nbr + (size_t)N * NPAD);
        ushort* mb  = xb + (size_t)N * DIN;
        ushort* W1L = mb + (size_t)N * DIN;
        ushort* W2L = W1L + 131072;

        hipMemsetAsync(cnt, 0, (size_t)N * sizeof(int), stream);
        prep_w<<<192, 256, 0, stream>>>(Wl, Wr, Wp, W1L, W2L);
        xcvt<<<((N * DIN / 4) + 255) / 256, 256, 0, stream>>>(x, xb, N * DIN / 4);
        fill_kernel<<<(E + 255) / 256, 256, 0, stream>>>(ei, cnt, nbr, E);
        agg_kernel<<<(N + 3) / 4, 256, 0, stream>>>(xb, cnt, nbr, mb, N);
        gemm_fused_kernel<<<(N + BMT - 1) / BMT, 1024, 0, stream>>>(xb, mb, W1L, W2L, bl, bp, out, N);
    }
}

// Round 18
// 264.928 us; speedup vs baseline: 5.9647x; 1.0382x over previous
//
#include <hip/hip_runtime.h>
#include <hip/hip_bf16.h>

#define DIN  128
#define HID  512
#define K1   256
#define NPAD 96       // fallback path only
#define BSH  8        // bucket = 256 dst nodes
#define CAPSH 13      // bucket capacity 8192 (mean 4081, ~64-sigma safe)
#define EPB  4096     // edges per bucket_kernel block

typedef __attribute__((ext_vector_type(8))) short short8;
typedef __attribute__((ext_vector_type(4))) float f32x4;

__device__ inline ushort bf16rne(float f) {
    union { float f; unsigned u; } c; c.f = f;
    unsigned b = c.u + 0x7fff + ((c.u >> 16) & 1);
    return (ushort)(b >> 16);
}
__device__ inline float bf16tof(unsigned lo16) {
    union { unsigned u; float f; } c; c.u = lo16 << 16;
    return c.f;
}
__device__ __forceinline__ void gld16(const void* g, void* l) {
    __builtin_amdgcn_global_load_lds((const __attribute__((address_space(1))) unsigned int*)g,
                                     (__attribute__((address_space(3))) unsigned int*)l, 16, 0, 0);
}
__device__ __forceinline__ void hard_barrier() {
    __builtin_amdgcn_sched_barrier(0);
    __builtin_amdgcn_s_barrier();
    __builtin_amdgcn_sched_barrier(0);
}

// ---------------------------------------------------------------------------
// fused: weights -> bf16 panelized image  +  x -> bf16
// ---------------------------------------------------------------------------
__global__ void prep_all(const float* __restrict__ Wl, const float* __restrict__ Wr,
                         const float* __restrict__ Wp,
                         ushort* __restrict__ W1L, ushort* __restrict__ W2L,
                         const float* __restrict__ x, ushort* __restrict__ xb, int total4) {
    if (blockIdx.x < 192) {
        int t = blockIdx.x * 256 + threadIdx.x;
        if (t < 8 * 4 * 512) {
            int p = t >> 11, c = (t >> 9) & 3, col = t & 511;
            int k0 = p * 32 + c * 8;
            #pragma unroll
            for (int r = 0; r < 8; ++r) {
                int k = k0 + r;
                float v = (k < DIN) ? Wl[k * HID + col] : Wr[(k - DIN) * HID + col];
                W1L[(size_t)t * 8 + r] = bf16rne(v);
            }
        } else {
            int t2 = t - 8 * 4 * 512;
            int p = t2 >> 11, c = (t2 >> 9) & 3, col = t2 & 511;
            int k0 = p * 32 + c * 8;
            #pragma unroll
            for (int r = 0; r < 8; ++r)
                W2L[(size_t)t2 * 8 + r] = bf16rne(Wp[(k0 + r) * HID + col]);
        }
    } else {
        int i = (blockIdx.x - 192) * 256 + threadIdx.x;
        if (i >= total4) return;
        const float4 v = ((const float4*)x)[i];
        ushort4 o;
        o.x = bf16rne(v.x); o.y = bf16rne(v.y); o.z = bf16rne(v.z); o.w = bf16rne(v.w);
        ((ushort4*)xb)[i] = o;
    }
}

// ---------------------------------------------------------------------------
// bucket pass: edges -> (dst>>8)-bucketed packed u32 (src<<8 | dst&255).
// Relative cursors (bcur zero-initialized by memset).
// ---------------------------------------------------------------------------
__global__ __launch_bounds__(256) void bucket_kernel(
    const int* __restrict__ ei, int* __restrict__ bcur,
    unsigned* __restrict__ eb, int E, int nb) {
    __shared__ int lhist[400], lbase[400], lcur[400];
    const int t = threadIdx.x;
    for (int i = t; i < nb; i += 256) lhist[i] = 0;
    __syncthreads();
    const int e0 = blockIdx.x * EPB;
    int srcs[16], dsts[16], bs[16];
    #pragma unroll
    for (int i = 0; i < 16; ++i) {
        int e = e0 + i * 256 + t;
        if (e < E) {
            srcs[i] = ei[e];
            dsts[i] = ei[E + e];
            bs[i] = dsts[i] >> BSH;
            atomicAdd(&lhist[bs[i]], 1);
        } else bs[i] = -1;
    }
    __syncthreads();
    for (int i = t; i < nb; i += 256) {
        lcur[i] = 0;
        if (lhist[i] > 0) lbase[i] = atomicAdd(&bcur[i], lhist[i]);
    }
    __syncthreads();
    #pragma unroll
    for (int i = 0; i < 16; ++i) {
        if (bs[i] >= 0) {
            int off = atomicAdd(&lcur[bs[i]], 1);
            int prel = lbase[bs[i]] + off;
            if (prel < (1 << CAPSH))
                eb[((size_t)bs[i] << CAPSH) + prel] = ((unsigned)srcs[i] << 8) | (unsigned)(dsts[i] & 255);
        }
    }
}

// ---------------------------------------------------------------------------
// agg3: one block per 256-node bucket, 1024 threads = 16 waves. LDS counting
// sort (hist -> scan -> scatter), then wave-per-node gather, 16/8/4/1 ladder.
// ---------------------------------------------------------------------------
__global__ __launch_bounds__(1024) void agg3_kernel(
    const ushort* __restrict__ xb, const unsigned* __restrict__ eb,
    const int* __restrict__ bcur, ushort* __restrict__ mb, int N) {
    __shared__ int sLDS[1 << CAPSH];          // sorted src list (32KB)
    __shared__ int pcnt[256], tmp[256], poff[256], pcur[256];
    const int t = threadIdx.x;
    const int l = t & 63;
    const int wv = t >> 6;                    // 0..15
    const int b = blockIdx.x;

    if (t < 256) pcnt[t] = 0;
    __syncthreads();

    const int vbase = b << CAPSH;
    int valid = bcur[b];
    if (valid > (1 << CAPSH)) valid = 1 << CAPSH;

    for (int i = t; i < valid; i += 1024)
        atomicAdd(&pcnt[eb[vbase + i] & 255u], 1);
    __syncthreads();

    if (t < 256) tmp[t] = pcnt[t];
    __syncthreads();
    #pragma unroll
    for (int s = 1; s < 256; s <<= 1) {
        int v = 0;
        if (t < 256) { v = tmp[t]; if (t >= s) v += tmp[t - s]; }
        __syncthreads();
        if (t < 256) tmp[t] = v;
        __syncthreads();
    }
    if (t < 256) { poff[t] = tmp[t] - pcnt[t]; pcur[t] = tmp[t] - pcnt[t]; }
    __syncthreads();

    for (int i = t; i < valid; i += 1024) {
        unsigned u = eb[vbase + i];
        int slot = atomicAdd(&pcur[u & 255u], 1);
        sLDS[slot] = (int)(u >> 8);
    }
    __syncthreads();

    for (int nl = wv; nl < 256; nl += 16) {
        int node = (b << BSH) + nl;
        if (node >= N) continue;
        int cn = pcnt[nl];
        const int off = poff[nl];
        float s0 = 0.f, s1 = 0.f;
        int i = 0;
        for (; i + 16 <= cn; i += 16) {
            int s_[16];
            #pragma unroll
            for (int j = 0; j < 16; ++j) s_[j] = sLDS[off + i + j];
            unsigned v_[16];
            #pragma unroll
            for (int j = 0; j < 16; ++j)
                v_[j] = ((const unsigned*)(xb + (size_t)s_[j] * DIN))[l];
            #pragma unroll
            for (int j = 0; j < 16; ++j) {
                s0 += bf16tof(v_[j] & 0xffffu);
                s1 += bf16tof(v_[j] >> 16);
            }
        }
        for (; i + 8 <= cn; i += 8) {
            int s_[8];
            #pragma unroll
            for (int j = 0; j < 8; ++j) s_[j] = sLDS[off + i + j];
            unsigned v_[8];
            #pragma unroll
            for (int j = 0; j < 8; ++j)
                v_[j] = ((const unsigned*)(xb + (size_t)s_[j] * DIN))[l];
            #pragma unroll
            for (int j = 0; j < 8; ++j) {
                s0 += bf16tof(v_[j] & 0xffffu);
                s1 += bf16tof(v_[j] >> 16);
            }
        }
        for (; i + 4 <= cn; i += 4) {
            int s_[4];
            #pragma unroll
            for (int j = 0; j < 4; ++j) s_[j] = sLDS[off + i + j];
            unsigned v_[4];
            #pragma unroll
            for (int j = 0; j < 4; ++j)
                v_[j] = ((const unsigned*)(xb + (size_t)s_[j] * DIN))[l];
            #pragma unroll
            for (int j = 0; j < 4; ++j) {
                s0 += bf16tof(v_[j] & 0xffffu);
                s1 += bf16tof(v_[j] >> 16);
            }
        }
        for (; i < cn; ++i) {
            int src = sLDS[off + i];
            unsigned v = ((const unsigned*)(xb + (size_t)src * DIN))[l];
            s0 += bf16tof(v & 0xffffu);
            s1 += bf16tof(v >> 16);
        }
        float rd = 1.0f / fmaxf((float)cn, 1.0f);
        unsigned o = (unsigned)bf16rne(s0 * rd) | ((unsigned)bf16rne(s1 * rd) << 16);
        ((unsigned*)(mb + (size_t)node * DIN))[l] = o;
    }
}

// ---------------------------------------------------------------------------
// fallback-path kernels (unbucketed nbr lists) + fallback prep/xcvt
// ---------------------------------------------------------------------------
__global__ void fill_kernel(const int* __restrict__ ei, int* __restrict__ cnt,
                            int* __restrict__ nbr, int E) {
    int e = blockIdx.x * blockDim.x + threadIdx.x;
    if (e >= E) return;
    int src = ei[e];
    int dst = ei[E + e];
    int pos = atomicAdd(cnt + dst, 1);
    if (pos < NPAD) nbr[(size_t)dst * NPAD + pos] = src;
}

__global__ __launch_bounds__(256) void agg_kernel(
    const ushort* __restrict__ xb, const int* __restrict__ cnt, const int* __restrict__ nbr,
    ushort* __restrict__ mb, int N) {
    int node = blockIdx.x * 4 + (threadIdx.x >> 6);
    if (node >= N) return;
    int l = threadIdx.x & 63;
    int cn = cnt[node];
    int cc = cn < NPAD ? cn : NPAD;
    const int* nl = nbr + (size_t)node * NPAD;
    float s0 = 0.f, s1 = 0.f;
    int i = 0;
    for (; i + 4 <= cc; i += 4) {
        int4 q = *(const int4*)(nl + i);
        unsigned v0 = ((const unsigned*)(xb + (size_t)q.x * DIN))[l];
        unsigned v1 = ((const unsigned*)(xb + (size_t)q.y * DIN))[l];
        unsigned v2 = ((const unsigned*)(xb + (size_t)q.z * DIN))[l];
        unsigned v3 = ((const unsigned*)(xb + (size_t)q.w * DIN))[l];
        s0 += bf16tof(v0 & 0xffffu) + bf16tof(v1 & 0xffffu) + bf16tof(v2 & 0xffffu) + bf16tof(v3 & 0xffffu);
        s1 += bf16tof(v0 >> 16) + bf16tof(v1 >> 16) + bf16tof(v2 >> 16) + bf16tof(v3 >> 16);
    }
    for (; i < cc; ++i) {
        int src = nl[i];
        unsigned v = ((const unsigned*)(xb + (size_t)src * DIN))[l];
        s0 += bf16tof(v & 0xffffu);
        s1 += bf16tof(v >> 16);
    }
    float rd = 1.0f / fmaxf((float)cn, 1.0f);
    unsigned o = (unsigned)bf16rne(s0 * rd) | ((unsigned)bf16rne(s1 * rd) << 16);
    ((unsigned*)(mb + (size_t)node * DIN))[l] = o;
}

// ===========================================================================
// Split-GEMM path (BMT2=128, wave tile 64x64). Counted-vmcnt double-barrier
// K-loop (T4): panel q+1 loads stay in flight across the barrier; per-wave
// outstanding counts: waves 0-7 stage A+W = 3 gld16/thread, waves 8-15 = 2.
// ===========================================================================
#define BMT2 128

__global__ __launch_bounds__(1024, 4) void gemm1_kernel(
    const ushort* __restrict__ xb, const ushort* __restrict__ mb,
    const ushort* __restrict__ W1L, const float* __restrict__ bl,
    ushort* __restrict__ Hb, int N) {
    __shared__ unsigned char sm[81920];
    const int t = threadIdx.x;
    const int l = t & 63, w = t >> 6;
    const int wm = w >> 3, wn = w & 7;
    const int lm = l & 15, ch = l >> 4;
    const int base = blockIdx.x * BMT2;

    // prologue: stage panel 0
    if (t < 512) {
        int c = t >> 7, row = t & 127;
        int node = base + row; if (node >= N) node = N - 1;
        gld16(mb + (size_t)node * DIN + c * 8, sm + t * 16);
    }
    gld16(W1L + (size_t)t * 8,          sm + 16384 + t * 16);
    gld16(W1L + (size_t)(t + 1024) * 8, sm + 16384 + (t + 1024) * 16);
    asm volatile("s_waitcnt vmcnt(0)" ::: "memory");
    hard_barrier();

    f32x4 acc[4][4];
    #pragma unroll
    for (int ct = 0; ct < 4; ++ct) {
        float bv = bl[wn * 64 + ct * 16 + lm];
        #pragma unroll
        for (int f = 0; f < 4; ++f) acc[f][ct] = (f32x4){bv, bv, bv, bv};
    }

    for (int p = 0; p < 8; ++p) {
        if (p < 7) {
            int nb = (p + 1) & 1;
            if (t < 512) {
                int c = t >> 7, row = t & 127;
                int node = base + row; if (node >= N) node = N - 1;
                int k0 = (p + 1) * 32 + c * 8;
                const ushort* src = (k0 < DIN) ? (mb + (size_t)node * DIN + k0)
                                               : (xb + (size_t)node * DIN + (k0 - DIN));
                gld16(src, sm + nb * 8192 + t * 16);
            }
            const ushort* wsrc = W1L + (size_t)(p + 1) * 16384;
            gld16(wsrc + (size_t)t * 8,          sm + 16384 + nb * 32768 + t * 16);
            gld16(wsrc + (size_t)(t + 1024) * 8, sm + 16384 + nb * 32768 + (t + 1024) * 16);
            if (t < 512) asm volatile("s_waitcnt vmcnt(3)" ::: "memory");
            else         asm volatile("s_waitcnt vmcnt(2)" ::: "memory");
        } else {
            asm volatile("s_waitcnt vmcnt(0)" ::: "memory");
        }
        hard_barrier();
        const unsigned ab = (p & 1) * 8192;
        const unsigned bb = 16384 + (p & 1) * 32768;
        short8 a[4], b[4];
        #pragma unroll
        for (int f = 0; f < 4; ++f)
            a[f] = *(const short8*)(sm + ab + (ch * 128 + wm * 64 + f * 16 + lm) * 16);
        #pragma unroll
        for (int ct = 0; ct < 4; ++ct)
            b[ct] = *(const short8*)(sm + bb + (ch * 512 + wn * 64 + ct * 16 + lm) * 16);
        #pragma unroll
        for (int f = 0; f < 4; ++f)
            #pragma unroll
            for (int ct = 0; ct < 4; ++ct)
                acc[f][ct] = __builtin_amdgcn_mfma_f32_16x16x32_bf16(a[f], b[ct], acc[f][ct], 0, 0, 0);
        hard_barrier();
    }

    #pragma unroll
    for (int f = 0; f < 4; ++f)
        #pragma unroll
        for (int ct = 0; ct < 4; ++ct) {
            int n = wn * 64 + ct * 16 + lm;
            #pragma unroll
            for (int r = 0; r < 4; ++r) {
                int m = wm * 64 + f * 16 + ch * 4 + r;
                int node = base + m;
                if (node < N) Hb[(size_t)node * HID + n] = bf16rne(fmaxf(acc[f][ct][r], 0.0f));
            }
        }
}

__global__ __launch_bounds__(1024, 4) void gemm2_kernel(
    const ushort* __restrict__ Hb, const ushort* __restrict__ W2L,
    const float* __restrict__ bp, float* __restrict__ out, int N) {
    __shared__ unsigned char sm[81920];
    const int t = threadIdx.x;
    const int l = t & 63, w = t >> 6;
    const int wm = w >> 3, wn = w & 7;
    const int lm = l & 15, ch = l >> 4;
    const int base = blockIdx.x * BMT2;

    if (t < 512) {
        int c = t >> 7, row = t & 127;
        int node = base + row; if (node >= N) node = N - 1;
        gld16(Hb + (size_t)node * HID + c * 8, sm + t * 16);
    }
    gld16(W2L + (size_t)t * 8,          sm + 16384 + t * 16);
    gld16(W2L + (size_t)(t + 1024) * 8, sm + 16384 + (t + 1024) * 16);
    asm volatile("s_waitcnt vmcnt(0)" ::: "memory");
    hard_barrier();

    f32x4 d[4][4];
    #pragma unroll
    for (int ct = 0; ct < 4; ++ct) {
        float bv = bp[wn * 64 + ct * 16 + lm];
        #pragma unroll
        for (int f = 0; f < 4; ++f) d[f][ct] = (f32x4){bv, bv, bv, bv};
    }

    for (int q = 0; q < 16; ++q) {
        if (q < 15) {
            int nb = (q + 1) & 1;
            if (t < 512) {
                int c = t >> 7, row = t & 127;
                int node = base + row; if (node >= N) node = N - 1;
                gld16(Hb + (size_t)node * HID + (q + 1) * 32 + c * 8, sm + nb * 8192 + t * 16);
            }
            const ushort* wsrc = W2L + (size_t)(q + 1) * 16384;
            gld16(wsrc + (size_t)t * 8,          sm + 16384 + nb * 32768 + t * 16);
            gld16(wsrc + (size_t)(t + 1024) * 8, sm + 16384 + nb * 32768 + (t + 1024) * 16);
            if (t < 512) asm volatile("s_waitcnt vmcnt(3)" ::: "memory");
            else         asm volatile("s_waitcnt vmcnt(2)" ::: "memory");
        } else {
            asm volatile("s_waitcnt vmcnt(0)" ::: "memory");
        }
        hard_barrier();
        const unsigned ab = (q & 1) * 8192;
        const unsigned bb = 16384 + (q & 1) * 32768;
        short8 a[4], b[4];
        #pragma unroll
        for (int f = 0; f < 4; ++f)
            a[f] = *(const short8*)(sm + ab + (ch * 128 + wm * 64 + f * 16 + lm) * 16);
        #pragma unroll
        for (int ct = 0; ct < 4; ++ct)
            b[ct] = *(const short8*)(sm + bb + (ch * 512 + wn * 64 + ct * 16 + lm) * 16);
        #pragma unroll
        for (int f = 0; f < 4; ++f)
            #pragma unroll
            for (int ct = 0; ct < 4; ++ct)
                d[f][ct] = __builtin_amdgcn_mfma_f32_16x16x32_bf16(a[f], b[ct], d[f][ct], 0, 0, 0);
        hard_barrier();
    }

    #pragma unroll
    for (int f = 0; f < 4; ++f)
        #pragma unroll
        for (int ct = 0; ct < 4; ++ct) {
            int n = wn * 64 + ct * 16 + lm;
            #pragma unroll
            for (int r = 0; r < 4; ++r) {
                int m = wm * 64 + f * 16 + ch * 4 + r;
                int node = base + m;
                if (node < N) out[(size_t)node * HID + n] = d[f][ct][r];
            }
        }
}

// ===========================================================================
// Fallback: fused kernel (ws too small for split buffers)
// ===========================================================================
#define BMT 64
__global__ __launch_bounds__(1024, 4) void gemm_fused_kernel(
    const ushort* __restrict__ xb, const ushort* __restrict__ mb,
    const ushort* __restrict__ W1L, const ushort* __restrict__ W2L,
    const float* __restrict__ bl, const float* __restrict__ bp,
    float* __restrict__ out, int N) {
    __shared__ unsigned char sm[131072];
    const int t = threadIdx.x;
    const int l = t & 63;
    const int w = t >> 6;
    const int wm = w >> 3;
    const int wn = w & 7;
    const int lm = l & 15;
    const int ch = l >> 4;
    const int base = blockIdx.x * BMT;

    #pragma unroll
    for (int j = 0; j < 2; ++j) {
        int idx = w * 128 + j * 64 + l;
        int p = idx >> 8, c = (idx >> 6) & 3, row = idx & 63;
        int node = base + row;
        if (node >= N) node = N - 1;
        int k0 = p * 32 + c * 8;
        const ushort* src = (k0 < DIN) ? (mb + (size_t)node * DIN + k0)
                                       : (xb + (size_t)node * DIN + (k0 - DIN));
        gld16(src, sm + idx * 16);
    }
    #pragma unroll
    for (int j = 0; j < 2; ++j) {
        int ci = w * 128 + j * 64 + l;
        gld16(W1L + (size_t)ci * 8, sm + 32768 + ci * 16);
    }
    __syncthreads();

    f32x4 acc[2][4];
    #pragma unroll
    for (int ct = 0; ct < 4; ++ct) {
        float bv = bl[wn * 64 + ct * 16 + lm];
        acc[0][ct] = (f32x4){bv, bv, bv, bv};
        acc[1][ct] = acc[0][ct];
    }
    for (int p = 0; p < 8; ++p) {
        if (p < 7) {
            const ushort* wsrc = W1L + (size_t)(p + 1) * 16384;
            unsigned boff = 32768 + (((p + 1) & 1) << 15);
            #pragma unroll
            for (int j = 0; j < 2; ++j) {
                int ci = w * 128 + j * 64 + l;
                gld16(wsrc + (size_t)ci * 8, sm + boff + ci * 16);
            }
        }
        const unsigned abase = (p * 256 + ch * 64) * 16;
        const unsigned bbase = 32768 + ((p & 1) << 15) + ch * 8192;
        short8 a[2], b[4];
        #pragma unroll
        for (int f = 0; f < 2; ++f)
            a[f] = *(const short8*)(sm + abase + (wm * 32 + f * 16 + lm) * 16);
        #pragma unroll
        for (int ct = 0; ct < 4; ++ct)
            b[ct] = *(const short8*)(sm + bbase + (wn * 64 + ct * 16 + lm) * 16);
        #pragma unroll
        for (int f = 0; f < 2; ++f)
            #pragma unroll
            for (int ct = 0; ct < 4; ++ct)
                acc[f][ct] = __builtin_amdgcn_mfma_f32_16x16x32_bf16(a[f], b[ct], acc[f][ct], 0, 0, 0);
        __syncthreads();
    }

    #pragma unroll
    for (int j = 0; j < 2; ++j) {
        int ci = w * 128 + j * 64 + l;
        gld16(W2L + (size_t)ci * 8, sm + 65536 + ci * 16);
    }
    #pragma unroll
    for (int f = 0; f < 2; ++f)
        #pragma unroll
        for (int ct = 0; ct < 4; ++ct) {
            int n = wn * 64 + ct * 16 + lm;
            unsigned hb = ((n >> 5) * 256 + ((n >> 3) & 3) * 64) * 16 + (n & 7) * 2;
            #pragma unroll
            for (int r = 0; r < 4; ++r) {
                int m = wm * 32 + f * 16 + ch * 4 + r;
                *(ushort*)(sm + hb + m * 16) = bf16rne(fmaxf(acc[f][ct][r], 0.0f));
            }
        }
    __syncthreads();

    f32x4 d[2][4];
    #pragma unroll
    for (int ct = 0; ct < 4; ++ct) {
        float bv = bp[wn * 64 + ct * 16 + lm];
        d[0][ct] = (f32x4){bv, bv, bv, bv};
        d[1][ct] = d[0][ct];
    }
    for (int q = 0; q < 16; ++q) {
        if (q < 15) {
            const ushort* wsrc = W2L + (size_t)(q + 1) * 16384;
            unsigned boff = 65536 + (((q + 1) & 1) << 15);
            #pragma unroll
            for (int j = 0; j < 2; ++j) {
                int ci = w * 128 + j * 64 + l;
                gld16(wsrc + (size_t)ci * 8, sm + boff + ci * 16);
            }
        }
        const unsigned abase = (q * 256 + ch * 64) * 16;
        const unsigned bbase = 65536 + ((q & 1) << 15) + ch * 8192;
        short8 a[2], b[4];
        #pragma unroll
        for (int f = 0; f < 2; ++f)
            a[f] = *(const short8*)(sm + abase + (wm * 32 + f * 16 + lm) * 16);
        #pragma unroll
        for (int ct = 0; ct < 4; ++ct)
            b[ct] = *(const short8*)(sm + bbase + (wn * 64 + ct * 16 + lm) * 16);
        #pragma unroll
        for (int f = 0; f < 2; ++f)
            #pragma unroll
            for (int ct = 0; ct < 4; ++ct)
                d[f][ct] = __builtin_amdgcn_mfma_f32_16x16x32_bf16(a[f], b[ct], d[f][ct], 0, 0, 0);
        __syncthreads();
    }

    #pragma unroll
    for (int f = 0; f < 2; ++f)
        #pragma unroll
        for (int ct = 0; ct < 4; ++ct) {
            int n = wn * 64 + ct * 16 + lm;
            #pragma unroll
            for (int r = 0; r < 4; ++r) {
                int m = wm * 32 + f * 16 + ch * 4 + r;
                int node = base + m;
                if (node < N) out[(size_t)node * HID + n] = d[f][ct][r];
            }
        }
}

// fallback-only prep kernels
__global__ void prep_w(const float* __restrict__ Wl, const float* __restrict__ Wr,
                       const float* __restrict__ Wp,
                       ushort* __restrict__ W1L, ushort* __restrict__ W2L) {
    int t = blockIdx.x * blockDim.x + threadIdx.x;
    if (t < 8 * 4 * 512) {
        int p = t >> 11, c = (t >> 9) & 3, col = t & 511;
        int k0 = p * 32 + c * 8;
        #pragma unroll
        for (int r = 0; r < 8; ++r) {
            int k = k0 + r;
            float v = (k < DIN) ? Wl[k * HID + col] : Wr[(k - DIN) * HID + col];
            W1L[(size_t)t * 8 + r] = bf16rne(v);
        }
    } else if (t < 8 * 4 * 512 + 16 * 4 * 512) {
        int t2 = t - 8 * 4 * 512;
        int p = t2 >> 11, c = (t2 >> 9) & 3, col = t2 & 511;
        int k0 = p * 32 + c * 8;
        #pragma unroll
        for (int r = 0; r < 8; ++r)
            W2L[(size_t)t2 * 8 + r] = bf16rne(Wp[(k0 + r) * HID + col]);
    }
}

__global__ void xcvt(const float* __restrict__ x, ushort* __restrict__ xb, int total4) {
    int i = blockIdx.x * blockDim.x + threadIdx.x;
    if (i >= total4) return;
    const float4 v = ((const float4*)x)[i];
    ushort4 o;
    o.x = bf16rne(v.x); o.y = bf16rne(v.y); o.z = bf16rne(v.z); o.w = bf16rne(v.w);
    ((ushort4*)xb)[i] = o;
}

extern "C" void kernel_launch(void* const* d_in, const int* in_sizes, int n_in,
                              void* d_out, int out_size, void* d_ws, size_t ws_size,
                              hipStream_t stream) {
    const float* x  = (const float*)d_in[0];
    const int*   ei = (const int*)d_in[1];
    const float* Wl = (const float*)d_in[2];
    const float* bl = (const float*)d_in[3];
    const float* Wr = (const float*)d_in[4];
    const float* Wp = (const float*)d_in[5];
    const float* bp = (const float*)d_in[6];
    float* out = (float*)d_out;

    const int N = in_sizes[0] / DIN;
    const int E = in_sizes[1] / 2;
    const int NB = (N + 255) >> BSH;                                  // 391 buckets
    const int total4 = N * DIN / 4;

    const size_t hBytes  = (size_t)N * HID * sizeof(ushort);          // 102.4 MB
    const size_t xbBytes = (size_t)N * DIN * sizeof(ushort);          // 25.6 MB
    const size_t w1Bytes = 131072 * sizeof(ushort);
    const size_t w2Bytes = 262144 * sizeof(ushort);
    const size_t bucketBytes = ((size_t)NB << CAPSH) * sizeof(unsigned) + NB * sizeof(int);
    const size_t needBig = hBytes + 2 * xbBytes + w1Bytes + w2Bytes;  // ~154.4 MB

    if (ws_size >= needBig && bucketBytes <= hBytes && N < (1 << 24) && NB <= 400) {
        char* base = (char*)d_ws;
        // bucket scratch overlays the Hb region (dead before gemm1)
        unsigned* eb  = (unsigned*)base;                  // NB<<CAPSH u32
        int*      bcur = (int*)(eb + ((size_t)NB << CAPSH));
        ushort* Hb   = (ushort*)base;
        ushort* xb   = (ushort*)(base + hBytes);
        ushort* mb   = (ushort*)(base + hBytes + xbBytes);
        ushort* W1L  = (ushort*)(base + hBytes + 2 * xbBytes);
        ushort* W2L  = (ushort*)((char*)W1L + w1Bytes);

        hipMemsetAsync(bcur, 0, (size_t)NB * sizeof(int), stream);
        prep_all<<<192 + (total4 + 255) / 256, 256, 0, stream>>>(Wl, Wr, Wp, W1L, W2L, x, xb, total4);
        bucket_kernel<<<(E + EPB - 1) / EPB, 256, 0, stream>>>(ei, bcur, eb, E, NB);
        agg3_kernel<<<NB, 1024, 0, stream>>>(xb, eb, bcur, mb, N);
        int g = (N + BMT2 - 1) / BMT2;
        gemm1_kernel<<<g, 1024, 0, stream>>>(xb, mb, W1L, bl, Hb, N);
        gemm2_kernel<<<g, 1024, 0, stream>>>(Hb, W2L, bp, out, N);
    } else {
        int*    cnt = (int*)d_ws;
        int*    nbr = cnt + N;
        ushort* xb  = (ushort*)(nbr + (size_t)N * NPAD);
        ushort* mb  = xb + (size_t)N * DIN;
        ushort* W1L = mb + (size_t)N * DIN;
        ushort* W2L = W1L + 131072;

        hipMemsetAsync(cnt, 0, (size_t)N * sizeof(int), stream);
        prep_w<<<192, 256, 0, stream>>>(Wl, Wr, Wp, W1L, W2L);
        xcvt<<<(total4 + 255) / 256, 256, 0, stream>>>(x, xb, total4);
        fill_kernel<<<(E + 255) / 256, 256, 0, stream>>>(ei, cnt, nbr, E);
        agg_kernel<<<(N + 3) / 4, 256, 0, stream>>>(xb, cnt, nbr, mb, N);
        gemm_fused_kernel<<<(N + BMT - 1) / BMT, 1024, 0, stream>>>(xb, mb, W1L, W2L, bl, bp, out, N);
    }
}